// Round 1
// 11187.498 us; speedup vs baseline: 1.1658x; 1.1658x over previous
//
#include <hip/hip_runtime.h>
#include <hip/hip_fp16.h>
#include <math.h>

// ---------------------------------------------------------------------------
// Decoder (ESPnet AttDot + 2x LSTMCell + CE) on gfx950.
// R4 -> R5: weight-stationary recurrent GEMMs (persistent-RNN style).
//  R4 flaw: w0cat/w1cat (37.8 MB) re-streamed from HBM every step as MFMA
//  B-operands (FETCH 4.08 GB ~= 31.6 MB/step at 362 GB/s == 90 us/step).
//  Now each block preloads its weight slice into VGPRs once:
//   g0: 256 blocks x 16 gate-rows, K=2560 4-way wave-split -> 80 VGPR/thr
//   g1: 128 blocks x 32 gate-rows, K=2048 2-way wave-split -> 128 VGPR/thr
//  Partial K-sums combined in LDS at gate finalize. Grid 288 -> 416 (all
//  co-resident at 2 blocks/CU under launch_bounds(256,2)); barrier widened
//  to 16 sub-counters. Dataflow, phases, and att role unchanged.
// ---------------------------------------------------------------------------

typedef _Float16 f16;
typedef _Float16 f16x2 __attribute__((ext_vector_type(2)));
typedef _Float16 f16x4 __attribute__((ext_vector_type(4)));
typedef _Float16 f16x8 __attribute__((ext_vector_type(8)));
typedef float f32x4 __attribute__((ext_vector_type(4)));

#define SOS_ID 9999
#define NB 32
#define NTT 512
#define NE 512
#define ND 1024
#define NA 320
#define NO 10000
#define NL 129
#define NTOK (NL*NB)
#define NG0 256
#define NG1 128
#define GRID_LOOP 416   // 256 g0 + 128 g1 + 32 att

union PU32 { unsigned u; f16x2 h; };
union PU64 { unsigned long long u; f16x4 h; unsigned w[2]; };

__device__ __forceinline__ float fdot2f(f16x2 a, f16x2 b, float c) {
#if __has_builtin(__builtin_amdgcn_fdot2)
  return __builtin_amdgcn_fdot2(a, b, c, false);
#else
  return c + (float)a[0]*(float)b[0] + (float)a[1]*(float)b[1];
#endif
}
__device__ __forceinline__ float dot8(f16x8 a, f16x8 b, float acc) {
  acc = fdot2f(__builtin_shufflevector(a, a, 0, 1), __builtin_shufflevector(b, b, 0, 1), acc);
  acc = fdot2f(__builtin_shufflevector(a, a, 2, 3), __builtin_shufflevector(b, b, 2, 3), acc);
  acc = fdot2f(__builtin_shufflevector(a, a, 4, 5), __builtin_shufflevector(b, b, 4, 5), acc);
  acc = fdot2f(__builtin_shufflevector(a, a, 6, 7), __builtin_shufflevector(b, b, 6, 7), acc);
  return acc;
}
__device__ __forceinline__ float sigf(float x) { return 1.0f / (1.0f + __expf(-x)); }
__device__ __forceinline__ float tanhf_fast(float x) { return 1.0f - 2.0f / (1.0f + __expf(2.0f * x)); }

__device__ __forceinline__ unsigned long long aload64(const void* p) {
  return __hip_atomic_load((const unsigned long long*)p, __ATOMIC_RELAXED, __HIP_MEMORY_SCOPE_AGENT);
}
__device__ __forceinline__ void astore32(void* p, unsigned v) {
  __hip_atomic_store((unsigned*)p, v, __ATOMIC_RELAXED, __HIP_MEMORY_SCOPE_AGENT);
}
__device__ __forceinline__ unsigned pack2(float a, float b) {
  PU32 u; u.h[0] = (f16)a; u.h[1] = (f16)b; return u.u;
}

// Two-level monotonic barrier (16 sub-counters + root + flag). No acquire
// fences anywhere: mutable data moves via agent-scope atomics only.
__device__ __forceinline__ void gbar2(unsigned* bar, int bid, unsigned idx) {
  __syncthreads();
  if (threadIdx.x == 0) {
    unsigned old = __hip_atomic_fetch_add(&bar[(bid & 15) * 32], 1u, __ATOMIC_RELEASE, __HIP_MEMORY_SCOPE_AGENT);
    if (old + 1u == idx * (GRID_LOOP / 16)) {
      unsigned r = __hip_atomic_fetch_add(&bar[500], 1u, __ATOMIC_RELEASE, __HIP_MEMORY_SCOPE_AGENT);
      if (r + 1u == idx * 16u)
        __hip_atomic_store(&bar[508], idx, __ATOMIC_RELEASE, __HIP_MEMORY_SCOPE_AGENT);
    }
    while (__hip_atomic_load(&bar[508], __ATOMIC_RELAXED, __HIP_MEMORY_SCOPE_AGENT) < idx)
      __builtin_amdgcn_s_sleep(8);
  }
  __syncthreads();
  asm volatile("" ::: "memory");
}

// ------------------------------ prep kernels -------------------------------
__global__ void k_cvt(const float* __restrict__ s, f16* __restrict__ d, long n) {
  long i = (long)blockIdx.x * 256 + threadIdx.x;
  long st = (long)gridDim.x * 256;
  for (; i < n; i += st) d[i] = (f16)s[i];
}
// w0cat cols: [0:1024)=Wih0 ey part, [1024:2048)=Whh0 (z0prev), [2048:2560)=Wih0 att part
__global__ void k_w0cat(const float* __restrict__ wih, const float* __restrict__ whh, f16* __restrict__ dst) {
  int j = blockIdx.y; int k = blockIdx.x * 256 + threadIdx.x;
  float v;
  if (k < 1024)      v = wih[(long)j * 1536 + k];
  else if (k < 2048) v = whh[(long)j * 1024 + (k - 1024)];
  else               v = wih[(long)j * 1536 + 1024 + (k - 2048)];
  dst[(long)j * 2560 + k] = (f16)v;
}
// w1cat cols: [0:1024)=Wih1 (z0), [1024:2048)=Whh1 (z1prev)
__global__ void k_w1cat(const float* __restrict__ wih, const float* __restrict__ whh, f16* __restrict__ dst) {
  int j = blockIdx.y; int k = blockIdx.x * 256 + threadIdx.x;
  float v = (k < 1024) ? wih[(long)j * 1024 + k] : whh[(long)j * 1024 + (k - 1024)];
  dst[(long)j * 2048 + k] = (f16)v;
}
__global__ void k_eys(const int* __restrict__ ys, const float* __restrict__ emb, f16* __restrict__ eys) {
  int sb = blockIdx.y; int k = blockIdx.x * 256 + threadIdx.x;
  int s = sb >> 5, b = sb & 31;
  int tok = (s == 0) ? SOS_ID : ys[b * 128 + (s - 1)];
  eys[(long)sb * 1024 + k] = (f16)emb[(long)tok * 1024 + k];
}
// preT[b][a][t] = tanh(hs[b][t][:].wenc[a][:] + benc[a])  (t-contiguous)
__global__ void k_pre(const f16* __restrict__ hs, const f16* __restrict__ wenc,
                      const float* __restrict__ benc, f16* __restrict__ preT) {
  const int row0 = blockIdx.x * 32;
  for (int idx = threadIdx.x; idx < 32 * NA; idx += 256) {
    int r = row0 + idx / NA, a = idx % NA;
    const f16x8* hp = (const f16x8*)(hs + (long)r * NE);
    const f16x8* wp = (const f16x8*)(wenc + (long)a * NE);
    float acc = 0.f;
#pragma unroll 4
    for (int k = 0; k < 64; ++k) acc = dot8(hp[k], wp[k], acc);
    int b = r >> 9, t = r & 511;
    preT[((long)b * NA + a) * 512 + t] = (f16)tanhf_fast(acc + benc[a]);
  }
}
__global__ void k_bias(const float* a0, const float* b0, const float* a1, const float* b1,
                       float* s0, float* s1) {
  int i = blockIdx.x * 256 + threadIdx.x;
  if (i < 4096) { s0[i] = a0[i] + b0[i]; s1[i] = a1[i] + b1[i]; }
}
__global__ void k_zero(f16* dec, f16* z0, f16* z1, float* scal, unsigned* bar) {
  int i = blockIdx.x * 256 + threadIdx.x;
  if (i < NB * NA) dec[i] = (f16)0.f;
  if (i < NB * ND) { z0[i] = (f16)0.f; z1[i] = (f16)0.f; }
  if (i < 512) bar[i] = 0u;
  if (i < 8) scal[i] = 0.f;
}

// ------------------------------ persistent loop ----------------------------
struct LoopP {
  const f16 *preT, *hs, *eys, *w0, *w1, *wdec;
  const float *bs0, *bs1;
  const int* hlens;
  f16 *dec, *att, *z0h, *z1h, *zout;
  unsigned* bar;
};

__global__ void __launch_bounds__(256, 2) k_loop(LoopP p) {
  __shared__ __align__(16) f16 xs[32 * 520];   // 33280 B activation tile
  __shared__ float gacc[2176];                 // g0:[4][32][17] g1:[2][32][33] dec:[32][33] att:decF[320]
  __shared__ float cbuf[256];                  // c-state slice / att reduce

  const int bid = blockIdx.x, tid = threadIdx.x;
  const int wid = tid >> 6, lane = tid & 63, lr = lane & 15, lq = lane >> 4;
  cbuf[tid] = 0.f;
  __syncthreads();
  unsigned bidx = 0;

  // stage one 32x512 f16 tile into xs (row stride 520)
  auto stage = [&](const f16* src, long rs, bool atomic) {
    for (int idx = tid; idx < 4096; idx += 256) {
      int r = idx >> 7, c = idx & 127;
      const void* sp = (const void*)(src + (long)r * rs + c * 4);
      unsigned long long v = atomic ? aload64(sp) : *(const unsigned long long*)sp;
      *(unsigned long long*)(xs + r * 520 + c * 4) = v;
    }
  };

  if (bid < NG0) {
    // ===== role g0: 16 gate rows (4 hidden x 4 gates), K=2560 4-way split ==
    // Weight regs: wr[r] holds K-chunk c = (r<16 ? (r>>2)*16+(r&3)*4+par
    //                                          : 64+(r-16)*4+par), rows lr.
    const int par = wid;                         // K-chunk residue mod 4
    const f16* wb = p.w0 + (long)((lr >> 2) * 1024 + bid * 4 + (lr & 3)) * 2560 + lq * 8;
    f16x8 wr[20];
#pragma unroll
    for (int r = 0; r < 20; ++r) {
      const int c = (r < 16) ? ((r >> 2) * 16 + (r & 3) * 4 + par)
                             : (64 + (r - 16) * 4 + par);
      wr[r] = *(const f16x8*)(wb + c * 32);
    }
    const bool decduty = (bid < 20);
    const int a0 = bid * 16;
    const f16* wdrow = p.wdec + (long)(a0 + lr) * ND + lq * 8;
    const f16* ap0 = xs + lr * 520 + lq * 8;
    const f16* ap1 = xs + (16 + lr) * 520 + lq * 8;
    const float* bs = p.bs0;

    for (int s = 0; s < NL; ++s) {
      f32x4 acc0 = (f32x4){0.f, 0.f, 0.f, 0.f};
      f32x4 acc1 = (f32x4){0.f, 0.f, 0.f, 0.f};
      // ---- Phase A: ey (K 0:1024) + z0prev (K 1024:2048) ----
#pragma unroll
      for (int kt = 0; kt < 4; ++kt) {
        if (kt < 2) stage(p.eys + (long)s * (NB * ND) + kt * 512, ND, false);
        else        stage(p.z0h + (kt - 2) * 512, ND, true);
        __syncthreads();
#pragma unroll
        for (int j = 0; j < 4; ++j) {
          const int co = (4 * j + par) * 32;
          acc0 = __builtin_amdgcn_mfma_f32_16x16x32_f16(*(const f16x8*)(ap0 + co), wr[kt * 4 + j], acc0, 0, 0, 0);
          acc1 = __builtin_amdgcn_mfma_f32_16x16x32_f16(*(const f16x8*)(ap1 + co), wr[kt * 4 + j], acc1, 0, 0, 0);
        }
        __syncthreads();
      }
      gbar2(p.bar, bid, ++bidx);

      // ---- Phase B: att part (K 2048:2560) + finalize z0/c0 ----
      stage(p.att, NE, true);
      __syncthreads();
#pragma unroll
      for (int j = 0; j < 4; ++j) {
        const int co = (4 * j + par) * 32;
        acc0 = __builtin_amdgcn_mfma_f32_16x16x32_f16(*(const f16x8*)(ap0 + co), wr[16 + j], acc0, 0, 0, 0);
        acc1 = __builtin_amdgcn_mfma_f32_16x16x32_f16(*(const f16x8*)(ap1 + co), wr[16 + j], acc1, 0, 0, 0);
      }
#pragma unroll
      for (int reg = 0; reg < 4; ++reg) {
        gacc[par * 544 + (lq * 4 + reg) * 17 + lr]      = acc0[reg];
        gacc[par * 544 + (16 + lq * 4 + reg) * 17 + lr] = acc1[reg];
      }
      __syncthreads();
      if (tid < 64) {
        const int b = tid & 31, q = tid >> 5;   // q=0 -> hh 0,1 ; q=1 -> hh 2,3
        float z[2];
#pragma unroll
        for (int u = 0; u < 2; ++u) {
          const int hh = q * 2 + u;
          float gi = 0.f, gf = 0.f, gv = 0.f, go = 0.f;
#pragma unroll
          for (int pp = 0; pp < 4; ++pp) {
            const float* gp = gacc + pp * 544 + b * 17;
            gi += gp[hh]; gf += gp[4 + hh]; gv += gp[8 + hh]; go += gp[12 + hh];
          }
          const int hb = bid * 4 + hh;
          gi += bs[hb]; gf += bs[1024 + hb]; gv += bs[2048 + hb]; go += bs[3072 + hb];
          float cn = sigf(gf) * cbuf[b * 4 + hh] + sigf(gi) * tanhf_fast(gv);
          cbuf[b * 4 + hh] = cn;
          z[u] = sigf(go) * tanhf_fast(cn);
        }
        astore32((unsigned*)p.z0h + (b * ND + bid * 4) / 2 + q, pack2(z[0], z[1]));
      }
      gbar2(p.bar, bid, ++bidx);

      // ---- Phase C: dec(s+1) = tanh(z0 @ Wdec^T) on blocks 0..19 ----
      if (decduty) {
        f32x4 dacc = (f32x4){0.f, 0.f, 0.f, 0.f};
        for (int kt = 0; kt < 2; ++kt) {
          stage(p.z0h + kt * 512, ND, true);
          __syncthreads();
          if (wid < 2) {
            const f16* ap2 = xs + (wid * 16 + lr) * 520 + lq * 8;
            const f16* wk = wdrow + kt * 512;
#pragma unroll
            for (int kk = 0; kk < 512; kk += 32)
              dacc = __builtin_amdgcn_mfma_f32_16x16x32_f16(
                  *(const f16x8*)(ap2 + kk), *(const f16x8*)(wk + kk), dacc, 0, 0, 0);
          }
          __syncthreads();
        }
        if (wid < 2) {
#pragma unroll
          for (int reg = 0; reg < 4; ++reg)
            gacc[(wid * 16 + lq * 4 + reg) * 33 + lr] = tanhf_fast(dacc[reg]);
        }
        __syncthreads();
        {
          const int b = tid & 31, j = tid >> 5;  // j 0..7 covers 16 cols
          astore32((unsigned*)p.dec + (b * NA + a0) / 2 + j,
                   pack2(gacc[b * 33 + 2 * j], gacc[b * 33 + 2 * j + 1]));
        }
      }
      gbar2(p.bar, bid, ++bidx);
    }
  } else if (bid < NG0 + NG1) {
    // ===== role g1: 32 gate rows (8 hidden x 4 gates), K=2048 2-way split ==
    const int g1i = bid - NG0;
    const int rt = wid & 1, par = wid >> 1;      // rt: B-row tile, par: K residue
    const int rrow = rt * 16 + lr;
    const f16* wb = p.w1 + (long)((rrow >> 3) * 1024 + g1i * 8 + (rrow & 7)) * 2048 + lq * 8;
    f16x8 wr[32];
#pragma unroll
    for (int r = 0; r < 32; ++r) {
      const int c = (r < 16) ? ((r >> 3) * 16 + (r & 7) * 2 + par)
                             : (32 + ((r - 16) >> 3) * 16 + ((r - 16) & 7) * 2 + par);
      wr[r] = *(const f16x8*)(wb + c * 32);
    }
    const f16* ap0 = xs + lr * 520 + lq * 8;
    const f16* ap1 = xs + (16 + lr) * 520 + lq * 8;
    const float* bs = p.bs1;
    const int h0 = g1i * 8;

    for (int s = 0; s < NL; ++s) {
      f32x4 acc0 = (f32x4){0.f, 0.f, 0.f, 0.f};
      f32x4 acc1 = (f32x4){0.f, 0.f, 0.f, 0.f};
      // ---- Phase A: z1prev (K 1024:2048 -> regs 16..31) ----
#pragma unroll
      for (int kt = 0; kt < 2; ++kt) {
        stage(p.z1h + kt * 512, ND, true);
        __syncthreads();
#pragma unroll
        for (int j = 0; j < 8; ++j) {
          const int co = (2 * j + par) * 32;
          acc0 = __builtin_amdgcn_mfma_f32_16x16x32_f16(*(const f16x8*)(ap0 + co), wr[16 + kt * 8 + j], acc0, 0, 0, 0);
          acc1 = __builtin_amdgcn_mfma_f32_16x16x32_f16(*(const f16x8*)(ap1 + co), wr[16 + kt * 8 + j], acc1, 0, 0, 0);
        }
        __syncthreads();
      }
      gbar2(p.bar, bid, ++bidx);
      gbar2(p.bar, bid, ++bidx);
      // ---- Phase C: z0 part (K 0:1024 -> regs 0..15) + finalize z1/c1 ----
#pragma unroll
      for (int kt = 0; kt < 2; ++kt) {
        stage(p.z0h + kt * 512, ND, true);
        __syncthreads();
#pragma unroll
        for (int j = 0; j < 8; ++j) {
          const int co = (2 * j + par) * 32;
          acc0 = __builtin_amdgcn_mfma_f32_16x16x32_f16(*(const f16x8*)(ap0 + co), wr[kt * 8 + j], acc0, 0, 0, 0);
          acc1 = __builtin_amdgcn_mfma_f32_16x16x32_f16(*(const f16x8*)(ap1 + co), wr[kt * 8 + j], acc1, 0, 0, 0);
        }
        __syncthreads();
      }
#pragma unroll
      for (int reg = 0; reg < 4; ++reg) {
        gacc[par * 1056 + (lq * 4 + reg) * 33 + rrow]      = acc0[reg];
        gacc[par * 1056 + (16 + lq * 4 + reg) * 33 + rrow] = acc1[reg];
      }
      __syncthreads();
      if (tid < 128) {
        const int b = tid & 31, hp = tid >> 5;
        float z[2];
#pragma unroll
        for (int u = 0; u < 2; ++u) {
          const int hh = hp * 2 + u;
          float gi = gacc[b * 33 + hh]      + gacc[1056 + b * 33 + hh]      + bs[h0 + hh];
          float gf = gacc[b * 33 + 8 + hh]  + gacc[1056 + b * 33 + 8 + hh]  + bs[1024 + h0 + hh];
          float gv = gacc[b * 33 + 16 + hh] + gacc[1056 + b * 33 + 16 + hh] + bs[2048 + h0 + hh];
          float go = gacc[b * 33 + 24 + hh] + gacc[1056 + b * 33 + 24 + hh] + bs[3072 + h0 + hh];
          float cn = sigf(gf) * cbuf[b * 8 + hh] + sigf(gi) * tanhf_fast(gv);
          cbuf[b * 8 + hh] = cn;
          z[u] = sigf(go) * tanhf_fast(cn);
        }
        unsigned pk = pack2(z[0], z[1]);
        astore32((unsigned*)p.z1h + (b * ND + h0) / 2 + hp, pk);
        *((unsigned*)p.zout + ((long)(s * 32 + b) * ND + h0) / 2 + hp) = pk;
      }
      gbar2(p.bar, bid, ++bidx);
    }
  } else {
    // ================= role attention (one block per batch b) ==============
    const int b = bid - (NG0 + NG1);
    const int hlen = p.hlens[b];
    float* decF = gacc;            // [320]
    float* wL   = (float*)xs;      // [512]
    float* red  = cbuf;            // [4] per reduce
    const unsigned* pa  = (const unsigned*)p.preT + (long)b * NA * 256 + tid;
    const unsigned* hp2 = (const unsigned*)p.hs  + (long)b * NTT * 256 + tid;

    for (int s = 0; s < NL; ++s) {
      // ---- Phase A: e, softmax, att_c ----
      if (tid < 80) {
        PU64 v; v.u = aload64((const unsigned long long*)p.dec + b * 80 + tid);
#pragma unroll
        for (int i = 0; i < 4; ++i) decF[tid * 4 + i] = (float)v.h[i];
      }
      __syncthreads();
      float e0 = 0.f, e1 = 0.f;
#pragma unroll 4
      for (int a = 0; a < NA; ++a) {
        PU32 pv; pv.u = pa[(long)a * 256];
        float d = decF[a];
        e0 += (float)pv.h[0] * d;
        e1 += (float)pv.h[1] * d;
      }
      e0 *= 2.0f; e1 *= 2.0f;  // SCALING
      int t0 = 2 * tid, t1 = 2 * tid + 1;
      float m = fmaxf((t0 < hlen) ? e0 : -3e38f, (t1 < hlen) ? e1 : -3e38f);
#pragma unroll
      for (int off = 1; off < 64; off <<= 1) m = fmaxf(m, __shfl_xor(m, off));
      if (lane == 0) red[wid] = m;
      __syncthreads();
      const float M = fmaxf(fmaxf(red[0], red[1]), fmaxf(red[2], red[3]));
      float w0 = (t0 < hlen) ? __expf(e0 - M) : 0.f;
      float w1 = (t1 < hlen) ? __expf(e1 - M) : 0.f;
      wL[t0] = w0; wL[t1] = w1;
      float sm = w0 + w1;
#pragma unroll
      for (int off = 1; off < 64; off <<= 1) sm += __shfl_xor(sm, off);
      __syncthreads();               // wL visible + red reusable
      if (lane == 0) red[wid] = sm;
      __syncthreads();
      const float inv = 1.0f / (red[0] + red[1] + red[2] + red[3]);
      float a0 = 0.f, a1 = 0.f;
#pragma unroll 4
      for (int t = 0; t < hlen; ++t) {
        PU32 hv; hv.u = hp2[(long)t * 256];
        float w = wL[t];
        a0 += w * (float)hv.h[0];
        a1 += w * (float)hv.h[1];
      }
      astore32((unsigned*)p.att + b * 256 + tid, pack2(a0 * inv, a1 * inv));
      gbar2(p.bar, bid, ++bidx);
      gbar2(p.bar, bid, ++bidx);
      gbar2(p.bar, bid, ++bidx);
    }
  }
}

// ------------------------- logits GEMM + fused CE stats --------------------
__global__ void __launch_bounds__(256) k_lgemm(const f16* __restrict__ z, const f16* __restrict__ wout,
                                               const float* __restrict__ bout, float4* __restrict__ part) {
  const int mb = blockIdx.x, nb = blockIdx.y;
  const int wid = threadIdx.x >> 6, lane = threadIdx.x & 63;
  const int lr = lane & 15, lq = lane >> 4;
  const int m0 = mb * 32;
  const int n0 = nb * 512 + wid * 128;
  const f16* arow0 = z + (long)(m0 + lr) * 1024 + lq * 8;
  const f16* arow1 = arow0 + (long)16 * 1024;
  const f16* bp[8];
  int cols[8];
#pragma unroll
  for (int nt = 0; nt < 8; ++nt) {
    int n = n0 + nt * 16 + lr;
    cols[nt] = n;
    int nc = (n < NO) ? n : (NO - 1);
    bp[nt] = wout + (long)nc * 1024 + lq * 8;
  }
  f32x4 acc[16];
#pragma unroll
  for (int i = 0; i < 16; ++i) acc[i] = (f32x4){0.f, 0.f, 0.f, 0.f};
  for (int kk = 0; kk < 1024; kk += 32) {
    f16x8 a0v = *(const f16x8*)(arow0 + kk);
    f16x8 a1v = *(const f16x8*)(arow1 + kk);
#pragma unroll
    for (int nt = 0; nt < 8; ++nt) {
      f16x8 bv = *(const f16x8*)(bp[nt] + kk);
      acc[nt]     = __builtin_amdgcn_mfma_f32_16x16x32_f16(a0v, bv, acc[nt], 0, 0, 0);
      acc[8 + nt] = __builtin_amdgcn_mfma_f32_16x16x32_f16(a1v, bv, acc[8 + nt], 0, 0, 0);
    }
  }
  float bias[8];
#pragma unroll
  for (int nt = 0; nt < 8; ++nt) bias[nt] = (cols[nt] < NO) ? bout[cols[nt]] : 0.f;
  const int chunk = nb * 4 + wid;
#pragma unroll
  for (int mt = 0; mt < 2; ++mt) {
#pragma unroll
    for (int reg = 0; reg < 4; ++reg) {
      float vals[8];
      float mx = -1e30f, av = -1e30f; int ai = 0;
#pragma unroll
      for (int nt = 0; nt < 8; ++nt) {
        float v = (cols[nt] < NO) ? (acc[mt * 8 + nt][reg] + bias[nt]) : -1e30f;
        vals[nt] = v;
        mx = fmaxf(mx, v);
        if (v > av) { av = v; ai = cols[nt]; }
      }
      float sum = 0.f;
#pragma unroll
      for (int nt = 0; nt < 8; ++nt) sum += (vals[nt] > -9e29f) ? __expf(vals[nt] - mx) : 0.f;
#pragma unroll
      for (int off = 1; off < 16; off <<= 1) {
        float mo = __shfl_xor(mx, off);
        float so = __shfl_xor(sum, off);
        float avo = __shfl_xor(av, off);
        int aio = __shfl_xor(ai, off);
        float nm = fmaxf(mx, mo);
        float e1 = (mx > -9e29f) ? __expf(mx - nm) : 0.f;
        float e2 = (mo > -9e29f) ? __expf(mo - nm) : 0.f;
        sum = sum * e1 + so * e2;
        mx = nm;
        if (avo > av || (avo == av && aio < ai)) { av = avo; ai = aio; }
      }
      if (lr == 0) {
        int rowg = m0 + mt * 16 + lq * 4 + reg;
        float4 q; q.x = mx; q.y = sum; q.z = av; q.w = __int_as_float(ai);
        part[(long)rowg * 80 + chunk] = q;
      }
    }
  }
}

__global__ void k_tl(const f16* __restrict__ z, const f16* __restrict__ wout,
                     const float* __restrict__ bout, const int* __restrict__ ys, float* __restrict__ tl) {
  const int tok = blockIdx.x * 4 + (threadIdx.x >> 6);
  const int lane = threadIdx.x & 63;
  if (tok >= NTOK) return;
  const int s = tok >> 5, b = tok & 31;
  const int tgt = (s < 128) ? ys[b * 128 + s] : SOS_ID;
  const f16x8* zp = (const f16x8*)(z + (long)tok * 1024);
  const f16x8* wp = (const f16x8*)(wout + (long)tgt * 1024);
  float acc = 0.f;
  acc = dot8(zp[lane], wp[lane], acc);
  acc = dot8(zp[64 + lane], wp[64 + lane], acc);
#pragma unroll
  for (int off = 32; off > 0; off >>= 1) acc += __shfl_xor(acc, off);
  if (lane == 0) tl[tok] = acc + bout[tgt];
}

__global__ void k_ce(const float4* __restrict__ part, const float* __restrict__ tl,
                     const int* __restrict__ ys, float* scal) {
  const int m = blockIdx.x * 256 + threadIdx.x;
  float nll = 0.f, okf = 0.f;
  if (m < NTOK) {
    float M = -1e30f, S = 0.f, av = -1e30f; int ai = 0;
    for (int c = 0; c < 80; ++c) {
      float4 q = part[(long)m * 80 + c];
      float qm = q.x, qs = q.y, qa = q.z; int qi = __float_as_int(q.w);
      float nm = fmaxf(M, qm);
      float e1 = (M > -9e29f) ? __expf(M - nm) : 0.f;
      float e2 = (qm > -9e29f) ? __expf(qm - nm) : 0.f;
      S = S * e1 + qs * e2; M = nm;
      if (qa > av || (qa == av && qi < ai)) { av = qa; ai = qi; }
    }
    float lse = M + __logf(S);
    int s = m >> 5, b = m & 31;
    int tgt = (s < 128) ? ys[b * 128 + s] : SOS_ID;
    nll = lse - tl[m];
    okf = (ai == tgt) ? 1.f : 0.f;
  }
  __shared__ float r1[256], r2[256];
  r1[threadIdx.x] = nll; r2[threadIdx.x] = okf; __syncthreads();
  for (int st = 128; st > 0; st >>= 1) {
    if (threadIdx.x < st) { r1[threadIdx.x] += r1[threadIdx.x + st]; r2[threadIdx.x] += r2[threadIdx.x + st]; }
    __syncthreads();
  }
  if (threadIdx.x == 0) { atomicAdd(&scal[0], r1[0]); atomicAdd(&scal[1], r2[0]); }
}

__global__ void k_final(const float* scal, float* out) {
  if (threadIdx.x == 0) {
    float loss = scal[0] * (128.f / 4128.f);
    out[0] = loss;
    out[1] = scal[1] * (1.f / 4128.f);
    out[2] = expf(loss / 32.f);
  }
}

// --------------------------------- launch ----------------------------------
extern "C" void kernel_launch(void* const* d_in, const int* in_sizes, int n_in,
                              void* d_out, int out_size, void* d_ws, size_t ws_size,
                              hipStream_t stream) {
  const float* hs_pad = (const float*)d_in[0];
  const int* hlens    = (const int*)d_in[1];
  const int* ys_pad   = (const int*)d_in[2];
  const float* embed  = (const float*)d_in[3];
  const float* Wenc   = (const float*)d_in[4];
  const float* benc   = (const float*)d_in[5];
  const float* Wdec   = (const float*)d_in[6];
  const float* Wih0   = (const float*)d_in[7];
  const float* Whh0   = (const float*)d_in[8];
  const float* bih0   = (const float*)d_in[9];
  const float* bhh0   = (const float*)d_in[10];
  const float* Wih1   = (const float*)d_in[11];
  const float* Whh1   = (const float*)d_in[12];
  const float* bih1   = (const float*)d_in[13];
  const float* bhh1   = (const float*)d_in[14];
  const float* Wout   = (const float*)d_in[15];
  const float* bout   = (const float*)d_in[16];
  float* out = (float*)d_out;
  (void)in_sizes; (void)n_in; (void)out_size; (void)ws_size;

  char* ws = (char*)d_ws;
  size_t off = 0;
  auto alloc = [&](size_t bytes) -> char* {
    char* pp = ws + off;
    off = (off + bytes + 255) & ~(size_t)255;
    return pp;
  };
  f16* hs16    = (f16*)alloc((size_t)NB * NTT * NE * 2);
  f16* preT    = (f16*)alloc((size_t)NB * NA * NTT * 2);
  f16* eys16   = (f16*)alloc((size_t)NL * NB * ND * 2);
  f16* w0cat   = (f16*)alloc((size_t)4096 * 2560 * 2);
  f16* w1cat   = (f16*)alloc((size_t)4096 * 2048 * 2);
  f16* wdec16  = (f16*)alloc((size_t)NA * ND * 2);
  f16* wenc16  = (f16*)alloc((size_t)NA * NE * 2);
  f16* wout16  = (f16*)alloc((size_t)NO * ND * 2);
  f16* zout    = (f16*)alloc((size_t)NTOK * ND * 2);
  f16* z0h     = (f16*)alloc((size_t)NB * ND * 2);
  f16* z1h     = (f16*)alloc((size_t)NB * ND * 2);
  f16* dec16   = (f16*)alloc((size_t)NB * NA * 2);
  f16* att16   = (f16*)alloc((size_t)NB * NE * 2);
  float* bs0   = (float*)alloc(4096 * 4);
  float* bs1   = (float*)alloc(4096 * 4);
  float* tl    = (float*)alloc((size_t)NTOK * 4);
  float4* part = (float4*)alloc((size_t)NTOK * 80 * 16);
  float* scal  = (float*)alloc(256);
  unsigned* bar = (unsigned*)alloc(2048);

  k_cvt<<<dim3(2048), dim3(256), 0, stream>>>(hs_pad, hs16, (long)NB * NTT * NE);
  k_cvt<<<dim3(256), dim3(256), 0, stream>>>(Wdec, wdec16, (long)NA * ND);
  k_cvt<<<dim3(128), dim3(256), 0, stream>>>(Wenc, wenc16, (long)NA * NE);
  k_cvt<<<dim3(2048), dim3(256), 0, stream>>>(Wout, wout16, (long)NO * ND);
  k_w0cat<<<dim3(10, 4096), dim3(256), 0, stream>>>(Wih0, Whh0, w0cat);
  k_w1cat<<<dim3(8, 4096), dim3(256), 0, stream>>>(Wih1, Whh1, w1cat);
  k_eys<<<dim3(4, NL * NB), dim3(256), 0, stream>>>(ys_pad, embed, eys16);
  k_pre<<<dim3(512), dim3(256), 0, stream>>>(hs16, wenc16, benc, preT);
  k_bias<<<dim3(16), dim3(256), 0, stream>>>(bih0, bhh0, bih1, bhh1, bs0, bs1);
  k_zero<<<dim3(128), dim3(256), 0, stream>>>(dec16, z0h, z1h, scal, bar);

  LoopP lp;
  lp.preT = preT; lp.hs = hs16; lp.eys = eys16; lp.w0 = w0cat; lp.w1 = w1cat; lp.wdec = wdec16;
  lp.bs0 = bs0; lp.bs1 = bs1; lp.hlens = hlens;
  lp.dec = dec16; lp.att = att16; lp.z0h = z0h; lp.z1h = z1h; lp.zout = zout; lp.bar = bar;
  k_loop<<<dim3(GRID_LOOP), dim3(256), 0, stream>>>(lp);

  k_tl<<<dim3(NTOK / 4), dim3(256), 0, stream>>>(zout, wout16, bout, ys_pad, tl);
  k_lgemm<<<dim3(129, 20), dim3(256), 0, stream>>>(zout, wout16, bout, part);
  k_ce<<<dim3(17), dim3(256), 0, stream>>>(part, tl, ys_pad, scal);
  k_final<<<dim3(1), dim3(64), 0, stream>>>(scal, out);
}

// Round 2
// 9452.684 us; speedup vs baseline: 1.3798x; 1.1835x over previous
//
#include <hip/hip_runtime.h>
#include <hip/hip_fp16.h>
#include <math.h>

// ---------------------------------------------------------------------------
// Decoder (ESPnet AttDot + 2x LSTMCell + CE) on gfx950.
// R5 -> R6: latency-path surgery. R5 counters: nothing busy (HBM 0.4%,
// VALU 3.3%, Mfma 0.6%) -> pure serialization, 77us/step. Fixes:
//  - att role 4x parallel: e-loop wave-split over A (4x80) + 16B t-vector
//    loads; att_c wave-split over T (4x128) + 16B e-vector loads; LDS
//    partial reduction. Was ~19us of strided 4B loads on the critical path.
//  - double LDS tile buffer (2x 32x520): each phase stages its K-pair with
//    ONE barrier-latency unit instead of two sequential ones.
//  - eys(s+1) prefetched in Phase C by (otherwise idle) g0 blocks.
//  - barrier release flag replicated across 16 lines; s_sleep(1).
//  - weight frags pinned with asm "+v" (R5 VGPR_Count=124 < g1's 128-reg
//    weight set => compiler was re-materializing).
// ---------------------------------------------------------------------------

typedef _Float16 f16;
typedef _Float16 f16x2 __attribute__((ext_vector_type(2)));
typedef _Float16 f16x4 __attribute__((ext_vector_type(4)));
typedef _Float16 f16x8 __attribute__((ext_vector_type(8)));
typedef float f32x4 __attribute__((ext_vector_type(4)));

#define SOS_ID 9999
#define NB 32
#define NTT 512
#define NE 512
#define ND 1024
#define NA 320
#define NO 10000
#define NL 129
#define NTOK (NL*NB)
#define NG0 256
#define NG1 128
#define GRID_LOOP 416   // 256 g0 + 128 g1 + 32 att

union PU32 { unsigned u; f16x2 h; };
union PU64 { unsigned long long u; f16x4 h; unsigned w[2]; };

__device__ __forceinline__ float fdot2f(f16x2 a, f16x2 b, float c) {
#if __has_builtin(__builtin_amdgcn_fdot2)
  return __builtin_amdgcn_fdot2(a, b, c, false);
#else
  return c + (float)a[0]*(float)b[0] + (float)a[1]*(float)b[1];
#endif
}
__device__ __forceinline__ float dot8(f16x8 a, f16x8 b, float acc) {
  acc = fdot2f(__builtin_shufflevector(a, a, 0, 1), __builtin_shufflevector(b, b, 0, 1), acc);
  acc = fdot2f(__builtin_shufflevector(a, a, 2, 3), __builtin_shufflevector(b, b, 2, 3), acc);
  acc = fdot2f(__builtin_shufflevector(a, a, 4, 5), __builtin_shufflevector(b, b, 4, 5), acc);
  acc = fdot2f(__builtin_shufflevector(a, a, 6, 7), __builtin_shufflevector(b, b, 6, 7), acc);
  return acc;
}
__device__ __forceinline__ float sigf(float x) { return 1.0f / (1.0f + __expf(-x)); }
__device__ __forceinline__ float tanhf_fast(float x) { return 1.0f - 2.0f / (1.0f + __expf(2.0f * x)); }

__device__ __forceinline__ unsigned long long aload64(const void* p) {
  return __hip_atomic_load((const unsigned long long*)p, __ATOMIC_RELAXED, __HIP_MEMORY_SCOPE_AGENT);
}
__device__ __forceinline__ void astore32(void* p, unsigned v) {
  __hip_atomic_store((unsigned*)p, v, __ATOMIC_RELAXED, __HIP_MEMORY_SCOPE_AGENT);
}
__device__ __forceinline__ unsigned pack2(float a, float b) {
  PU32 u; u.h[0] = (f16)a; u.h[1] = (f16)b; return u.u;
}

// Two-level monotonic barrier (16 sub-counters + root + 16 replicated flags).
// No acquire fences: mutable data moves via agent-scope atomics only.
__device__ __forceinline__ void gbar2(unsigned* bar, int bid, unsigned idx) {
  __syncthreads();
  if (threadIdx.x == 0) {
    unsigned old = __hip_atomic_fetch_add(&bar[(bid & 15) * 32], 1u, __ATOMIC_RELEASE, __HIP_MEMORY_SCOPE_AGENT);
    if (old + 1u == idx * (GRID_LOOP / 16)) {
      unsigned r = __hip_atomic_fetch_add(&bar[500], 1u, __ATOMIC_RELEASE, __HIP_MEMORY_SCOPE_AGENT);
      if (r + 1u == idx * 16u) {
#pragma unroll
        for (int i = 0; i < 16; ++i)
          __hip_atomic_store(&bar[i * 32 + 16], idx, __ATOMIC_RELEASE, __HIP_MEMORY_SCOPE_AGENT);
      }
    }
    while (__hip_atomic_load(&bar[(bid & 15) * 32 + 16], __ATOMIC_RELAXED, __HIP_MEMORY_SCOPE_AGENT) < idx)
      __builtin_amdgcn_s_sleep(1);
  }
  __syncthreads();
  asm volatile("" ::: "memory");
}

// ------------------------------ prep kernels -------------------------------
__global__ void k_cvt(const float* __restrict__ s, f16* __restrict__ d, long n) {
  long i = (long)blockIdx.x * 256 + threadIdx.x;
  long st = (long)gridDim.x * 256;
  for (; i < n; i += st) d[i] = (f16)s[i];
}
// w0cat cols: [0:1024)=Wih0 ey part, [1024:2048)=Whh0 (z0prev), [2048:2560)=Wih0 att part
__global__ void k_w0cat(const float* __restrict__ wih, const float* __restrict__ whh, f16* __restrict__ dst) {
  int j = blockIdx.y; int k = blockIdx.x * 256 + threadIdx.x;
  float v;
  if (k < 1024)      v = wih[(long)j * 1536 + k];
  else if (k < 2048) v = whh[(long)j * 1024 + (k - 1024)];
  else               v = wih[(long)j * 1536 + 1024 + (k - 2048)];
  dst[(long)j * 2560 + k] = (f16)v;
}
// w1cat cols: [0:1024)=Wih1 (z0), [1024:2048)=Whh1 (z1prev)
__global__ void k_w1cat(const float* __restrict__ wih, const float* __restrict__ whh, f16* __restrict__ dst) {
  int j = blockIdx.y; int k = blockIdx.x * 256 + threadIdx.x;
  float v = (k < 1024) ? wih[(long)j * 1024 + k] : whh[(long)j * 1024 + (k - 1024)];
  dst[(long)j * 2048 + k] = (f16)v;
}
__global__ void k_eys(const int* __restrict__ ys, const float* __restrict__ emb, f16* __restrict__ eys) {
  int sb = blockIdx.y; int k = blockIdx.x * 256 + threadIdx.x;
  int s = sb >> 5, b = sb & 31;
  int tok = (s == 0) ? SOS_ID : ys[b * 128 + (s - 1)];
  eys[(long)sb * 1024 + k] = (f16)emb[(long)tok * 1024 + k];
}
// preT[b][a][t] = tanh(hs[b][t][:].wenc[a][:] + benc[a])  (t-contiguous)
__global__ void k_pre(const f16* __restrict__ hs, const f16* __restrict__ wenc,
                      const float* __restrict__ benc, f16* __restrict__ preT) {
  const int row0 = blockIdx.x * 32;
  for (int idx = threadIdx.x; idx < 32 * NA; idx += 256) {
    int r = row0 + idx / NA, a = idx % NA;
    const f16x8* hp = (const f16x8*)(hs + (long)r * NE);
    const f16x8* wp = (const f16x8*)(wenc + (long)a * NE);
    float acc = 0.f;
#pragma unroll 4
    for (int k = 0; k < 64; ++k) acc = dot8(hp[k], wp[k], acc);
    int b = r >> 9, t = r & 511;
    preT[((long)b * NA + a) * 512 + t] = (f16)tanhf_fast(acc + benc[a]);
  }
}
__global__ void k_bias(const float* a0, const float* b0, const float* a1, const float* b1,
                       float* s0, float* s1) {
  int i = blockIdx.x * 256 + threadIdx.x;
  if (i < 4096) { s0[i] = a0[i] + b0[i]; s1[i] = a1[i] + b1[i]; }
}
__global__ void k_zero(f16* dec, f16* z0, f16* z1, float* scal, unsigned* bar) {
  int i = blockIdx.x * 256 + threadIdx.x;
  if (i < NB * NA) dec[i] = (f16)0.f;
  if (i < NB * ND) { z0[i] = (f16)0.f; z1[i] = (f16)0.f; }
  if (i < 512) bar[i] = 0u;
  if (i < 8) scal[i] = 0.f;
}

// ------------------------------ persistent loop ----------------------------
struct LoopP {
  const f16 *preT, *hs, *eys, *w0, *w1, *wdec;
  const float *bs0, *bs1;
  const int* hlens;
  f16 *dec, *att, *z0h, *z1h, *zout;
  unsigned* bar;
};

__global__ void __launch_bounds__(256, 2) k_loop(LoopP p) {
  __shared__ __align__(16) f16 xs[2][32 * 520];  // 2 staging tiles, 66560 B
  __shared__ float gacc[2176];                   // gate partials / decF
  __shared__ float cbuf[256];                    // c-state slice / att reduce

  const int bid = blockIdx.x, tid = threadIdx.x;
  const int wid = tid >> 6, lane = tid & 63, lr = lane & 15, lq = lane >> 4;
  cbuf[tid] = 0.f;
  __syncthreads();
  unsigned bidx = 0;

  // stage one 32x512 f16 tile into dst (row stride 520)
  auto stage = [&](f16* dst, const f16* src, long rs, bool atomic) {
    for (int idx = tid; idx < 4096; idx += 256) {
      int r = idx >> 7, c = idx & 127;
      const void* sp = (const void*)(src + (long)r * rs + c * 4);
      unsigned long long v = atomic ? aload64(sp) : *(const unsigned long long*)sp;
      *(unsigned long long*)(dst + r * 520 + c * 4) = v;
    }
  };

  if (bid < NG0) {
    // ===== role g0: 16 gate rows (4 hidden x 4 gates), K=2560 4-way split ==
    const int par = wid;                         // K-chunk residue mod 4
    const f16* wb = p.w0 + (long)((lr >> 2) * 1024 + bid * 4 + (lr & 3)) * 2560 + lq * 8;
    f16x8 wr[20];
#pragma unroll
    for (int r = 0; r < 20; ++r) {
      const int c = (r < 16) ? ((r >> 2) * 16 + (r & 3) * 4 + par)
                             : (64 + (r - 16) * 4 + par);
      wr[r] = *(const f16x8*)(wb + c * 32);
    }
#pragma unroll
    for (int r = 0; r < 20; ++r) asm volatile("" : "+v"(wr[r]));  // pin in regs
    const bool decduty = (bid < 20);
    const int a0 = bid * 16;
    const f16* wdrow = p.wdec + (long)(a0 + lr) * ND + lq * 8;
    const f16* a00 = xs[0] + lr * 520 + lq * 8;
    const f16* a01 = a00 + 16 * 520;
    const f16* a10 = xs[1] + lr * 520 + lq * 8;
    const f16* a11 = a10 + 16 * 520;
    const float* bs = p.bs0;

    // prologue: eys(0) into both tiles
    stage(xs[0], p.eys, ND, false);
    stage(xs[1], p.eys + 512, ND, false);
    __syncthreads();

    for (int s = 0; s < NL; ++s) {
      f32x4 acc0 = (f32x4){0.f, 0.f, 0.f, 0.f};
      f32x4 acc1 = (f32x4){0.f, 0.f, 0.f, 0.f};
      // ---- Phase A: ey (prefetched) then z0prev ----
#pragma unroll
      for (int j = 0; j < 4; ++j) {
        const int co = (4 * j + par) * 32;
        acc0 = __builtin_amdgcn_mfma_f32_16x16x32_f16(*(const f16x8*)(a00 + co), wr[j], acc0, 0, 0, 0);
        acc1 = __builtin_amdgcn_mfma_f32_16x16x32_f16(*(const f16x8*)(a01 + co), wr[j], acc1, 0, 0, 0);
      }
#pragma unroll
      for (int j = 0; j < 4; ++j) {
        const int co = (4 * j + par) * 32;
        acc0 = __builtin_amdgcn_mfma_f32_16x16x32_f16(*(const f16x8*)(a10 + co), wr[4 + j], acc0, 0, 0, 0);
        acc1 = __builtin_amdgcn_mfma_f32_16x16x32_f16(*(const f16x8*)(a11 + co), wr[4 + j], acc1, 0, 0, 0);
      }
      __syncthreads();
      stage(xs[0], p.z0h, ND, true);
      stage(xs[1], p.z0h + 512, ND, true);
      __syncthreads();
#pragma unroll
      for (int j = 0; j < 4; ++j) {
        const int co = (4 * j + par) * 32;
        acc0 = __builtin_amdgcn_mfma_f32_16x16x32_f16(*(const f16x8*)(a00 + co), wr[8 + j], acc0, 0, 0, 0);
        acc1 = __builtin_amdgcn_mfma_f32_16x16x32_f16(*(const f16x8*)(a01 + co), wr[8 + j], acc1, 0, 0, 0);
      }
#pragma unroll
      for (int j = 0; j < 4; ++j) {
        const int co = (4 * j + par) * 32;
        acc0 = __builtin_amdgcn_mfma_f32_16x16x32_f16(*(const f16x8*)(a10 + co), wr[12 + j], acc0, 0, 0, 0);
        acc1 = __builtin_amdgcn_mfma_f32_16x16x32_f16(*(const f16x8*)(a11 + co), wr[12 + j], acc1, 0, 0, 0);
      }
      gbar2(p.bar, bid, ++bidx);

      // ---- Phase B: att part (K 2048:2560) + finalize z0/c0 ----
      stage(xs[0], p.att, NE, true);
      __syncthreads();
#pragma unroll
      for (int j = 0; j < 4; ++j) {
        const int co = (4 * j + par) * 32;
        acc0 = __builtin_amdgcn_mfma_f32_16x16x32_f16(*(const f16x8*)(a00 + co), wr[16 + j], acc0, 0, 0, 0);
        acc1 = __builtin_amdgcn_mfma_f32_16x16x32_f16(*(const f16x8*)(a01 + co), wr[16 + j], acc1, 0, 0, 0);
      }
#pragma unroll
      for (int reg = 0; reg < 4; ++reg) {
        gacc[par * 544 + (lq * 4 + reg) * 17 + lr]      = acc0[reg];
        gacc[par * 544 + (16 + lq * 4 + reg) * 17 + lr] = acc1[reg];
      }
      __syncthreads();
      if (tid < 64) {
        const int b = tid & 31, q = tid >> 5;   // q=0 -> hh 0,1 ; q=1 -> hh 2,3
        float z[2];
#pragma unroll
        for (int u = 0; u < 2; ++u) {
          const int hh = q * 2 + u;
          float gi = 0.f, gf = 0.f, gv = 0.f, go = 0.f;
#pragma unroll
          for (int pp = 0; pp < 4; ++pp) {
            const float* gp = gacc + pp * 544 + b * 17;
            gi += gp[hh]; gf += gp[4 + hh]; gv += gp[8 + hh]; go += gp[12 + hh];
          }
          const int hb = bid * 4 + hh;
          gi += bs[hb]; gf += bs[1024 + hb]; gv += bs[2048 + hb]; go += bs[3072 + hb];
          float cn = sigf(gf) * cbuf[b * 4 + hh] + sigf(gi) * tanhf_fast(gv);
          cbuf[b * 4 + hh] = cn;
          z[u] = sigf(go) * tanhf_fast(cn);
        }
        astore32((unsigned*)p.z0h + (b * ND + bid * 4) / 2 + q, pack2(z[0], z[1]));
      }
      gbar2(p.bar, bid, ++bidx);

      // ---- Phase C: dec(s+1) on blocks 0..19; everyone prefetches eys ----
      if (decduty) {
        f32x4 dacc = (f32x4){0.f, 0.f, 0.f, 0.f};
        stage(xs[0], p.z0h, ND, true);
        stage(xs[1], p.z0h + 512, ND, true);
        __syncthreads();
        if (wid < 2) {
#pragma unroll
          for (int kt = 0; kt < 2; ++kt) {
            const f16* ap2 = xs[kt] + (wid * 16 + lr) * 520 + lq * 8;
            const f16* wk = wdrow + kt * 512;
#pragma unroll
            for (int kk = 0; kk < 512; kk += 32)
              dacc = __builtin_amdgcn_mfma_f32_16x16x32_f16(
                  *(const f16x8*)(ap2 + kk), *(const f16x8*)(wk + kk), dacc, 0, 0, 0);
          }
        }
        __syncthreads();
        if (wid < 2) {
#pragma unroll
          for (int reg = 0; reg < 4; ++reg)
            gacc[(wid * 16 + lq * 4 + reg) * 33 + lr] = tanhf_fast(dacc[reg]);
        }
        __syncthreads();
        {
          const int b = tid & 31, j = tid >> 5;  // j 0..7 covers 16 cols
          astore32((unsigned*)p.dec + (b * NA + a0) / 2 + j,
                   pack2(gacc[b * 33 + 2 * j], gacc[b * 33 + 2 * j + 1]));
        }
        __syncthreads();
      }
      if (s + 1 < NL) {
        stage(xs[0], p.eys + (long)(s + 1) * (NB * ND), ND, false);
        stage(xs[1], p.eys + (long)(s + 1) * (NB * ND) + 512, ND, false);
      }
      gbar2(p.bar, bid, ++bidx);
    }
  } else if (bid < NG0 + NG1) {
    // ===== role g1: 32 gate rows (8 hidden x 4 gates), K=2048 2-way split ==
    const int g1i = bid - NG0;
    const int rt = wid & 1, par = wid >> 1;      // rt: N-row tile, par: K residue
    const int rrow = rt * 16 + lr;
    const f16* wb = p.w1 + (long)((rrow >> 3) * 1024 + g1i * 8 + (rrow & 7)) * 2048 + lq * 8;
    f16x8 wr[32];
#pragma unroll
    for (int r = 0; r < 32; ++r) {
      const int c = (r < 16) ? ((r >> 3) * 16 + (r & 7) * 2 + par)
                             : (32 + ((r - 16) >> 3) * 16 + ((r - 16) & 7) * 2 + par);
      wr[r] = *(const f16x8*)(wb + c * 32);
    }
#pragma unroll
    for (int r = 0; r < 32; ++r) asm volatile("" : "+v"(wr[r]));  // pin in regs
    const f16* a00 = xs[0] + lr * 520 + lq * 8;
    const f16* a01 = a00 + 16 * 520;
    const f16* a10 = xs[1] + lr * 520 + lq * 8;
    const f16* a11 = a10 + 16 * 520;
    const float* bs = p.bs1;
    const int h0 = g1i * 8;

    for (int s = 0; s < NL; ++s) {
      f32x4 acc0 = (f32x4){0.f, 0.f, 0.f, 0.f};
      f32x4 acc1 = (f32x4){0.f, 0.f, 0.f, 0.f};
      // ---- Phase A: z1prev (K 1024:2048 -> regs 16..31) ----
      stage(xs[0], p.z1h, ND, true);
      stage(xs[1], p.z1h + 512, ND, true);
      __syncthreads();
#pragma unroll
      for (int j = 0; j < 8; ++j) {
        const int co = (2 * j + par) * 32;
        acc0 = __builtin_amdgcn_mfma_f32_16x16x32_f16(*(const f16x8*)(a00 + co), wr[16 + j], acc0, 0, 0, 0);
        acc1 = __builtin_amdgcn_mfma_f32_16x16x32_f16(*(const f16x8*)(a01 + co), wr[16 + j], acc1, 0, 0, 0);
      }
#pragma unroll
      for (int j = 0; j < 8; ++j) {
        const int co = (2 * j + par) * 32;
        acc0 = __builtin_amdgcn_mfma_f32_16x16x32_f16(*(const f16x8*)(a10 + co), wr[24 + j], acc0, 0, 0, 0);
        acc1 = __builtin_amdgcn_mfma_f32_16x16x32_f16(*(const f16x8*)(a11 + co), wr[24 + j], acc1, 0, 0, 0);
      }
      gbar2(p.bar, bid, ++bidx);
      gbar2(p.bar, bid, ++bidx);
      // ---- Phase C: z0 part (K 0:1024 -> regs 0..15) + finalize z1/c1 ----
      stage(xs[0], p.z0h, ND, true);
      stage(xs[1], p.z0h + 512, ND, true);
      __syncthreads();
#pragma unroll
      for (int j = 0; j < 8; ++j) {
        const int co = (2 * j + par) * 32;
        acc0 = __builtin_amdgcn_mfma_f32_16x16x32_f16(*(const f16x8*)(a00 + co), wr[j], acc0, 0, 0, 0);
        acc1 = __builtin_amdgcn_mfma_f32_16x16x32_f16(*(const f16x8*)(a01 + co), wr[j], acc1, 0, 0, 0);
      }
#pragma unroll
      for (int j = 0; j < 8; ++j) {
        const int co = (2 * j + par) * 32;
        acc0 = __builtin_amdgcn_mfma_f32_16x16x32_f16(*(const f16x8*)(a10 + co), wr[8 + j], acc0, 0, 0, 0);
        acc1 = __builtin_amdgcn_mfma_f32_16x16x32_f16(*(const f16x8*)(a11 + co), wr[8 + j], acc1, 0, 0, 0);
      }
#pragma unroll
      for (int reg = 0; reg < 4; ++reg) {
        gacc[par * 1056 + (lq * 4 + reg) * 33 + rrow]      = acc0[reg];
        gacc[par * 1056 + (16 + lq * 4 + reg) * 33 + rrow] = acc1[reg];
      }
      __syncthreads();
      if (tid < 128) {
        const int b = tid & 31, hp = tid >> 5;
        float z[2];
#pragma unroll
        for (int u = 0; u < 2; ++u) {
          const int hh = hp * 2 + u;
          float gi = gacc[b * 33 + hh]      + gacc[1056 + b * 33 + hh]      + bs[h0 + hh];
          float gf = gacc[b * 33 + 8 + hh]  + gacc[1056 + b * 33 + 8 + hh]  + bs[1024 + h0 + hh];
          float gv = gacc[b * 33 + 16 + hh] + gacc[1056 + b * 33 + 16 + hh] + bs[2048 + h0 + hh];
          float go = gacc[b * 33 + 24 + hh] + gacc[1056 + b * 33 + 24 + hh] + bs[3072 + h0 + hh];
          float cn = sigf(gf) * cbuf[b * 8 + hh] + sigf(gi) * tanhf_fast(gv);
          cbuf[b * 8 + hh] = cn;
          z[u] = sigf(go) * tanhf_fast(cn);
        }
        unsigned pk = pack2(z[0], z[1]);
        astore32((unsigned*)p.z1h + (b * ND + h0) / 2 + hp, pk);
        *((unsigned*)p.zout + ((long)(s * 32 + b) * ND + h0) / 2 + hp) = pk;
      }
      gbar2(p.bar, bid, ++bidx);
    }
  } else {
    // ================= role attention (one block per batch b) ==============
    const int b = bid - (NG0 + NG1);
    const int hlen = p.hlens[b];
    float* epart = (float*)xs;             // [4][512]
    float* apart = (float*)xs + 2048;      // [4][512]
    float* wL    = (float*)xs + 4096;      // [512]
    float* decF  = gacc;                   // [320]
    float* red   = cbuf;                   // [4]
    const f16* pe  = p.preT + (long)b * NA * 512;   // [a][t]
    const f16* ph  = p.hs   + (long)b * 512 * 512;  // [t][e]

    for (int s = 0; s < NL; ++s) {
      // ---- Phase A: dec load, e (wave-split over A), softmax, att_c ----
      if (tid < 80) {
        PU64 v; v.u = aload64((const unsigned long long*)p.dec + b * 80 + tid);
#pragma unroll
        for (int i = 0; i < 4; ++i) decF[tid * 4 + i] = (float)v.h[i];
      }
      __syncthreads();
      // e partials: wave w covers a in [80w,80w+80); lane covers t-group 8*lane
      {
        float ea[8] = {0.f,0.f,0.f,0.f,0.f,0.f,0.f,0.f};
#pragma unroll 8
        for (int aa = 0; aa < 80; ++aa) {
          const int a = wid * 80 + aa;
          f16x8 pv = *(const f16x8*)(pe + (long)a * 512 + lane * 8);
          const float d = decF[a];
#pragma unroll
          for (int j = 0; j < 8; ++j) ea[j] += (float)pv[j] * d;
        }
#pragma unroll
        for (int j = 0; j < 8; ++j) epart[wid * 512 + lane * 8 + j] = ea[j];
      }
      __syncthreads();
      const int t0 = 2 * tid, t1 = 2 * tid + 1;
      float e0 = (epart[t0] + epart[512 + t0] + epart[1024 + t0] + epart[1536 + t0]) * 2.0f;
      float e1 = (epart[t1] + epart[512 + t1] + epart[1024 + t1] + epart[1536 + t1]) * 2.0f;
      float m = fmaxf((t0 < hlen) ? e0 : -3e38f, (t1 < hlen) ? e1 : -3e38f);
#pragma unroll
      for (int off = 1; off < 64; off <<= 1) m = fmaxf(m, __shfl_xor(m, off));
      if (lane == 0) red[wid] = m;
      __syncthreads();
      const float M = fmaxf(fmaxf(red[0], red[1]), fmaxf(red[2], red[3]));
      float w0 = (t0 < hlen) ? __expf(e0 - M) : 0.f;
      float w1 = (t1 < hlen) ? __expf(e1 - M) : 0.f;
      wL[t0] = w0; wL[t1] = w1;
      float sm = w0 + w1;
#pragma unroll
      for (int off = 1; off < 64; off <<= 1) sm += __shfl_xor(sm, off);
      __syncthreads();               // wL visible + red reusable
      if (lane == 0) red[wid] = sm;
      __syncthreads();
      const float inv = 1.0f / (red[0] + red[1] + red[2] + red[3]);
      // att_c partials: wave w covers t in [128w,128w+128); lane covers 8 e-cols
      {
        float ac[8] = {0.f,0.f,0.f,0.f,0.f,0.f,0.f,0.f};
#pragma unroll 8
        for (int tt = 0; tt < 128; ++tt) {
          const int t = wid * 128 + tt;
          f16x8 hv = *(const f16x8*)(ph + (long)t * 512 + lane * 8);
          const float w = wL[t];
#pragma unroll
          for (int j = 0; j < 8; ++j) ac[j] += (float)hv[j] * w;
        }
#pragma unroll
        for (int j = 0; j < 8; ++j) apart[wid * 512 + lane * 8 + j] = ac[j];
      }
      __syncthreads();
      {
        float s0 = apart[t0] + apart[512 + t0] + apart[1024 + t0] + apart[1536 + t0];
        float s1 = apart[t1] + apart[512 + t1] + apart[1024 + t1] + apart[1536 + t1];
        astore32((unsigned*)p.att + b * 256 + tid, pack2(s0 * inv, s1 * inv));
      }
      gbar2(p.bar, bid, ++bidx);
      gbar2(p.bar, bid, ++bidx);
      gbar2(p.bar, bid, ++bidx);
    }
  }
}

// ------------------------- logits GEMM + fused CE stats --------------------
__global__ void __launch_bounds__(256) k_lgemm(const f16* __restrict__ z, const f16* __restrict__ wout,
                                               const float* __restrict__ bout, float4* __restrict__ part) {
  const int mb = blockIdx.x, nb = blockIdx.y;
  const int wid = threadIdx.x >> 6, lane = threadIdx.x & 63;
  const int lr = lane & 15, lq = lane >> 4;
  const int m0 = mb * 32;
  const int n0 = nb * 512 + wid * 128;
  const f16* arow0 = z + (long)(m0 + lr) * 1024 + lq * 8;
  const f16* arow1 = arow0 + (long)16 * 1024;
  const f16* bp[8];
  int cols[8];
#pragma unroll
  for (int nt = 0; nt < 8; ++nt) {
    int n = n0 + nt * 16 + lr;
    cols[nt] = n;
    int nc = (n < NO) ? n : (NO - 1);
    bp[nt] = wout + (long)nc * 1024 + lq * 8;
  }
  f32x4 acc[16];
#pragma unroll
  for (int i = 0; i < 16; ++i) acc[i] = (f32x4){0.f, 0.f, 0.f, 0.f};
  for (int kk = 0; kk < 1024; kk += 32) {
    f16x8 a0v = *(const f16x8*)(arow0 + kk);
    f16x8 a1v = *(const f16x8*)(arow1 + kk);
#pragma unroll
    for (int nt = 0; nt < 8; ++nt) {
      f16x8 bv = *(const f16x8*)(bp[nt] + kk);
      acc[nt]     = __builtin_amdgcn_mfma_f32_16x16x32_f16(a0v, bv, acc[nt], 0, 0, 0);
      acc[8 + nt] = __builtin_amdgcn_mfma_f32_16x16x32_f16(a1v, bv, acc[8 + nt], 0, 0, 0);
    }
  }
  float bias[8];
#pragma unroll
  for (int nt = 0; nt < 8; ++nt) bias[nt] = (cols[nt] < NO) ? bout[cols[nt]] : 0.f;
  const int chunk = nb * 4 + wid;
#pragma unroll
  for (int mt = 0; mt < 2; ++mt) {
#pragma unroll
    for (int reg = 0; reg < 4; ++reg) {
      float vals[8];
      float mx = -1e30f, av = -1e30f; int ai = 0;
#pragma unroll
      for (int nt = 0; nt < 8; ++nt) {
        float v = (cols[nt] < NO) ? (acc[mt * 8 + nt][reg] + bias[nt]) : -1e30f;
        vals[nt] = v;
        mx = fmaxf(mx, v);
        if (v > av) { av = v; ai = cols[nt]; }
      }
      float sum = 0.f;
#pragma unroll
      for (int nt = 0; nt < 8; ++nt) sum += (vals[nt] > -9e29f) ? __expf(vals[nt] - mx) : 0.f;
#pragma unroll
      for (int off = 1; off < 16; off <<= 1) {
        float mo = __shfl_xor(mx, off);
        float so = __shfl_xor(sum, off);
        float avo = __shfl_xor(av, off);
        int aio = __shfl_xor(ai, off);
        float nm = fmaxf(mx, mo);
        float e1 = (mx > -9e29f) ? __expf(mx - nm) : 0.f;
        float e2 = (mo > -9e29f) ? __expf(mo - nm) : 0.f;
        sum = sum * e1 + so * e2;
        mx = nm;
        if (avo > av || (avo == av && aio < ai)) { av = avo; ai = aio; }
      }
      if (lr == 0) {
        int rowg = m0 + mt * 16 + lq * 4 + reg;
        float4 q; q.x = mx; q.y = sum; q.z = av; q.w = __int_as_float(ai);
        part[(long)rowg * 80 + chunk] = q;
      }
    }
  }
}

__global__ void k_tl(const f16* __restrict__ z, const f16* __restrict__ wout,
                     const float* __restrict__ bout, const int* __restrict__ ys, float* __restrict__ tl) {
  const int tok = blockIdx.x * 4 + (threadIdx.x >> 6);
  const int lane = threadIdx.x & 63;
  if (tok >= NTOK) return;
  const int s = tok >> 5, b = tok & 31;
  const int tgt = (s < 128) ? ys[b * 128 + s] : SOS_ID;
  const f16x8* zp = (const f16x8*)(z + (long)tok * 1024);
  const f16x8* wp = (const f16x8*)(wout + (long)tgt * 1024);
  float acc = 0.f;
  acc = dot8(zp[lane], wp[lane], acc);
  acc = dot8(zp[64 + lane], wp[64 + lane], acc);
#pragma unroll
  for (int off = 32; off > 0; off >>= 1) acc += __shfl_xor(acc, off);
  if (lane == 0) tl[tok] = acc + bout[tgt];
}

__global__ void k_ce(const float4* __restrict__ part, const float* __restrict__ tl,
                     const int* __restrict__ ys, float* scal) {
  const int m = blockIdx.x * 256 + threadIdx.x;
  float nll = 0.f, okf = 0.f;
  if (m < NTOK) {
    float M = -1e30f, S = 0.f, av = -1e30f; int ai = 0;
    for (int c = 0; c < 80; ++c) {
      float4 q = part[(long)m * 80 + c];
      float qm = q.x, qs = q.y, qa = q.z; int qi = __float_as_int(q.w);
      float nm = fmaxf(M, qm);
      float e1 = (M > -9e29f) ? __expf(M - nm) : 0.f;
      float e2 = (qm > -9e29f) ? __expf(qm - nm) : 0.f;
      S = S * e1 + qs * e2; M = nm;
      if (qa > av || (qa == av && qi < ai)) { av = qa; ai = qi; }
    }
    float lse = M + __logf(S);
    int s = m >> 5, b = m & 31;
    int tgt = (s < 128) ? ys[b * 128 + s] : SOS_ID;
    nll = lse - tl[m];
    okf = (ai == tgt) ? 1.f : 0.f;
  }
  __shared__ float r1[256], r2[256];
  r1[threadIdx.x] = nll; r2[threadIdx.x] = okf; __syncthreads();
  for (int st = 128; st > 0; st >>= 1) {
    if (threadIdx.x < st) { r1[threadIdx.x] += r1[threadIdx.x + st]; r2[threadIdx.x] += r2[threadIdx.x + st]; }
    __syncthreads();
  }
  if (threadIdx.x == 0) { atomicAdd(&scal[0], r1[0]); atomicAdd(&scal[1], r2[0]); }
}

__global__ void k_final(const float* scal, float* out) {
  if (threadIdx.x == 0) {
    float loss = scal[0] * (128.f / 4128.f);
    out[0] = loss;
    out[1] = scal[1] * (1.f / 4128.f);
    out[2] = expf(loss / 32.f);
  }
}

// --------------------------------- launch ----------------------------------
extern "C" void kernel_launch(void* const* d_in, const int* in_sizes, int n_in,
                              void* d_out, int out_size, void* d_ws, size_t ws_size,
                              hipStream_t stream) {
  const float* hs_pad = (const float*)d_in[0];
  const int* hlens    = (const int*)d_in[1];
  const int* ys_pad   = (const int*)d_in[2];
  const float* embed  = (const float*)d_in[3];
  const float* Wenc   = (const float*)d_in[4];
  const float* benc   = (const float*)d_in[5];
  const float* Wdec   = (const float*)d_in[6];
  const float* Wih0   = (const float*)d_in[7];
  const float* Whh0   = (const float*)d_in[8];
  const float* bih0   = (const float*)d_in[9];
  const float* bhh0   = (const float*)d_in[10];
  const float* Wih1   = (const float*)d_in[11];
  const float* Whh1   = (const float*)d_in[12];
  const float* bih1   = (const float*)d_in[13];
  const float* bhh1   = (const float*)d_in[14];
  const float* Wout   = (const float*)d_in[15];
  const float* bout   = (const float*)d_in[16];
  float* out = (float*)d_out;
  (void)in_sizes; (void)n_in; (void)out_size; (void)ws_size;

  char* ws = (char*)d_ws;
  size_t off = 0;
  auto alloc = [&](size_t bytes) -> char* {
    char* pp = ws + off;
    off = (off + bytes + 255) & ~(size_t)255;
    return pp;
  };
  f16* hs16    = (f16*)alloc((size_t)NB * NTT * NE * 2);
  f16* preT    = (f16*)alloc((size_t)NB * NA * NTT * 2);
  f16* eys16   = (f16*)alloc((size_t)NL * NB * ND * 2);
  f16* w0cat   = (f16*)alloc((size_t)4096 * 2560 * 2);
  f16* w1cat   = (f16*)alloc((size_t)4096 * 2048 * 2);
  f16* wdec16  = (f16*)alloc((size_t)NA * ND * 2);
  f16* wenc16  = (f16*)alloc((size_t)NA * NE * 2);
  f16* wout16  = (f16*)alloc((size_t)NO * ND * 2);
  f16* zout    = (f16*)alloc((size_t)NTOK * ND * 2);
  f16* z0h     = (f16*)alloc((size_t)NB * ND * 2);
  f16* z1h     = (f16*)alloc((size_t)NB * ND * 2);
  f16* dec16   = (f16*)alloc((size_t)NB * NA * 2);
  f16* att16   = (f16*)alloc((size_t)NB * NE * 2);
  float* bs0   = (float*)alloc(4096 * 4);
  float* bs1   = (float*)alloc(4096 * 4);
  float* tl    = (float*)alloc((size_t)NTOK * 4);
  float4* part = (float4*)alloc((size_t)NTOK * 80 * 16);
  float* scal  = (float*)alloc(256);
  unsigned* bar = (unsigned*)alloc(2048);

  k_cvt<<<dim3(2048), dim3(256), 0, stream>>>(hs_pad, hs16, (long)NB * NTT * NE);
  k_cvt<<<dim3(256), dim3(256), 0, stream>>>(Wdec, wdec16, (long)NA * ND);
  k_cvt<<<dim3(128), dim3(256), 0, stream>>>(Wenc, wenc16, (long)NA * NE);
  k_cvt<<<dim3(2048), dim3(256), 0, stream>>>(Wout, wout16, (long)NO * ND);
  k_w0cat<<<dim3(10, 4096), dim3(256), 0, stream>>>(Wih0, Whh0, w0cat);
  k_w1cat<<<dim3(8, 4096), dim3(256), 0, stream>>>(Wih1, Whh1, w1cat);
  k_eys<<<dim3(4, NL * NB), dim3(256), 0, stream>>>(ys_pad, embed, eys16);
  k_pre<<<dim3(512), dim3(256), 0, stream>>>(hs16, wenc16, benc, preT);
  k_bias<<<dim3(16), dim3(256), 0, stream>>>(bih0, bhh0, bih1, bhh1, bs0, bs1);
  k_zero<<<dim3(128), dim3(256), 0, stream>>>(dec16, z0h, z1h, scal, bar);

  LoopP lp;
  lp.preT = preT; lp.hs = hs16; lp.eys = eys16; lp.w0 = w0cat; lp.w1 = w1cat; lp.wdec = wdec16;
  lp.bs0 = bs0; lp.bs1 = bs1; lp.hlens = hlens;
  lp.dec = dec16; lp.att = att16; lp.z0h = z0h; lp.z1h = z1h; lp.zout = zout; lp.bar = bar;
  k_loop<<<dim3(GRID_LOOP), dim3(256), 0, stream>>>(lp);

  k_tl<<<dim3(NTOK / 4), dim3(256), 0, stream>>>(zout, wout16, bout, ys_pad, tl);
  k_lgemm<<<dim3(129, 20), dim3(256), 0, stream>>>(zout, wout16, bout, part);
  k_ce<<<dim3(17), dim3(256), 0, stream>>>(part, tl, ys_pad, scal);
  k_final<<<dim3(1), dim3(64), 0, stream>>>(scal, out);
}

// Round 3
// 6707.374 us; speedup vs baseline: 1.9445x; 1.4093x over previous
//
#include <hip/hip_runtime.h>
#include <hip/hip_fp16.h>
#include <math.h>

// ---------------------------------------------------------------------------
// Decoder (ESPnet AttDot + 2x LSTMCell + CE) on gfx950.
// R6 -> R7: producer/consumer signals instead of full grid barriers.
//  R6 counters: nothing busy (VALU 4.1%, Mfma 0.8%), 65us/step with 3 full
//  barriers x ~21us. The dependency cycle dec->att->z0->dec only needs
//  group-complete signals. Four monotonic counting signals (sub->root->
//  replicated flags), producers fire-and-continue, consumers spin:
//    sz0 (256 g0) -> g1, dec-duty, g0-next-step
//    sz1 (128 g1) -> g1 (z1prev)
//    satt (32 att) -> g0 Phase B
//    sdec (20 dec-duty) -> att
//  All cross-step state is write-once sequenced: z0seq[s], z1 from zout[s]
//  (now agent-scope stores); dec/att single-buffer (transitively ordered).
//  g1 falls off the critical cycle. Expected ~12-15us/step.
// ---------------------------------------------------------------------------

typedef _Float16 f16;
typedef _Float16 f16x2 __attribute__((ext_vector_type(2)));
typedef _Float16 f16x4 __attribute__((ext_vector_type(4)));
typedef _Float16 f16x8 __attribute__((ext_vector_type(8)));
typedef float f32x4 __attribute__((ext_vector_type(4)));

#define SOS_ID 9999
#define NB 32
#define NTT 512
#define NE 512
#define ND 1024
#define NA 320
#define NO 10000
#define NL 129
#define NTOK (NL*NB)
#define NG0 256
#define NG1 128
#define GRID_LOOP 416   // 256 g0 + 128 g1 + 32 att

// signal slot indices (unsigned slots, stride 32 = one 128B line each)
#define S_SZ0  0
#define R_SZ0  16
#define S_SZ1  17
#define R_SZ1  25
#define S_SATT 26
#define R_SATT 30
#define S_SDEC 31
#define R_SDEC 35
#define F_SZ0  64
#define F_SZ1  80
#define F_SATT 88
#define F_SDEC 104

union PU32 { unsigned u; f16x2 h; };
union PU64 { unsigned long long u; f16x4 h; unsigned w[2]; };

__device__ __forceinline__ float fdot2f(f16x2 a, f16x2 b, float c) {
#if __has_builtin(__builtin_amdgcn_fdot2)
  return __builtin_amdgcn_fdot2(a, b, c, false);
#else
  return c + (float)a[0]*(float)b[0] + (float)a[1]*(float)b[1];
#endif
}
__device__ __forceinline__ float dot8(f16x8 a, f16x8 b, float acc) {
  acc = fdot2f(__builtin_shufflevector(a, a, 0, 1), __builtin_shufflevector(b, b, 0, 1), acc);
  acc = fdot2f(__builtin_shufflevector(a, a, 2, 3), __builtin_shufflevector(b, b, 2, 3), acc);
  acc = fdot2f(__builtin_shufflevector(a, a, 4, 5), __builtin_shufflevector(b, b, 4, 5), acc);
  acc = fdot2f(__builtin_shufflevector(a, a, 6, 7), __builtin_shufflevector(b, b, 6, 7), acc);
  return acc;
}
__device__ __forceinline__ float sigf(float x) { return 1.0f / (1.0f + __expf(-x)); }
__device__ __forceinline__ float tanhf_fast(float x) { return 1.0f - 2.0f / (1.0f + __expf(2.0f * x)); }

__device__ __forceinline__ unsigned long long aload64(const void* p) {
  return __hip_atomic_load((const unsigned long long*)p, __ATOMIC_RELAXED, __HIP_MEMORY_SCOPE_AGENT);
}
__device__ __forceinline__ void astore32(void* p, unsigned v) {
  __hip_atomic_store((unsigned*)p, v, __ATOMIC_RELAXED, __HIP_MEMORY_SCOPE_AGENT);
}
__device__ __forceinline__ unsigned pack2(float a, float b) {
  PU32 u; u.h[0] = (f16)a; u.h[1] = (f16)b; return u.u;
}

// producer-side signal: sub counter -> root counter -> replicated flags.
// Called by thread 0 after __syncthreads() (all block stores drained).
__device__ __forceinline__ void sigstep(unsigned* bar, int sub, unsigned subtgt,
                                        int root, unsigned roottgt,
                                        int flag0, int nrep, unsigned val) {
  unsigned old = __hip_atomic_fetch_add(&bar[sub * 32], 1u, __ATOMIC_RELEASE, __HIP_MEMORY_SCOPE_AGENT);
  if (old + 1u == subtgt) {
    unsigned r = __hip_atomic_fetch_add(&bar[root * 32], 1u, __ATOMIC_RELEASE, __HIP_MEMORY_SCOPE_AGENT);
    if (r + 1u == roottgt) {
      for (int i = 0; i < nrep; ++i)
        __hip_atomic_store(&bar[(flag0 + i) * 32], val, __ATOMIC_RELEASE, __HIP_MEMORY_SCOPE_AGENT);
    }
  }
}
// consumer-side wait on a replicated flag
__device__ __forceinline__ void waitflag(unsigned* bar, int slot, unsigned val) {
  if (threadIdx.x == 0) {
    while (__hip_atomic_load(&bar[slot * 32], __ATOMIC_RELAXED, __HIP_MEMORY_SCOPE_AGENT) < val)
      __builtin_amdgcn_s_sleep(1);
  }
  __syncthreads();
  asm volatile("" ::: "memory");
}

// ------------------------------ prep kernels -------------------------------
__global__ void k_cvt(const float* __restrict__ s, f16* __restrict__ d, long n) {
  long i = (long)blockIdx.x * 256 + threadIdx.x;
  long st = (long)gridDim.x * 256;
  for (; i < n; i += st) d[i] = (f16)s[i];
}
// w0cat cols: [0:1024)=Wih0 ey part, [1024:2048)=Whh0 (z0prev), [2048:2560)=Wih0 att part
__global__ void k_w0cat(const float* __restrict__ wih, const float* __restrict__ whh, f16* __restrict__ dst) {
  int j = blockIdx.y; int k = blockIdx.x * 256 + threadIdx.x;
  float v;
  if (k < 1024)      v = wih[(long)j * 1536 + k];
  else if (k < 2048) v = whh[(long)j * 1024 + (k - 1024)];
  else               v = wih[(long)j * 1536 + 1024 + (k - 2048)];
  dst[(long)j * 2560 + k] = (f16)v;
}
// w1cat cols: [0:1024)=Wih1 (z0), [1024:2048)=Whh1 (z1prev)
__global__ void k_w1cat(const float* __restrict__ wih, const float* __restrict__ whh, f16* __restrict__ dst) {
  int j = blockIdx.y; int k = blockIdx.x * 256 + threadIdx.x;
  float v = (k < 1024) ? wih[(long)j * 1024 + k] : whh[(long)j * 1024 + (k - 1024)];
  dst[(long)j * 2048 + k] = (f16)v;
}
__global__ void k_eys(const int* __restrict__ ys, const float* __restrict__ emb, f16* __restrict__ eys) {
  int sb = blockIdx.y; int k = blockIdx.x * 256 + threadIdx.x;
  int s = sb >> 5, b = sb & 31;
  int tok = (s == 0) ? SOS_ID : ys[b * 128 + (s - 1)];
  eys[(long)sb * 1024 + k] = (f16)emb[(long)tok * 1024 + k];
}
// preT[b][a][t] = tanh(hs[b][t][:].wenc[a][:] + benc[a])  (t-contiguous)
__global__ void k_pre(const f16* __restrict__ hs, const f16* __restrict__ wenc,
                      const float* __restrict__ benc, f16* __restrict__ preT) {
  const int row0 = blockIdx.x * 32;
  for (int idx = threadIdx.x; idx < 32 * NA; idx += 256) {
    int r = row0 + idx / NA, a = idx % NA;
    const f16x8* hp = (const f16x8*)(hs + (long)r * NE);
    const f16x8* wp = (const f16x8*)(wenc + (long)a * NE);
    float acc = 0.f;
#pragma unroll 4
    for (int k = 0; k < 64; ++k) acc = dot8(hp[k], wp[k], acc);
    int b = r >> 9, t = r & 511;
    preT[((long)b * NA + a) * 512 + t] = (f16)tanhf_fast(acc + benc[a]);
  }
}
__global__ void k_bias(const float* a0, const float* b0, const float* a1, const float* b1,
                       float* s0, float* s1) {
  int i = blockIdx.x * 256 + threadIdx.x;
  if (i < 4096) { s0[i] = a0[i] + b0[i]; s1[i] = a1[i] + b1[i]; }
}
__global__ void k_zero(f16* dec, float* scal, unsigned* bar) {
  int i = blockIdx.x * 256 + threadIdx.x;
  if (i < NB * NA) dec[i] = (f16)0.f;
  if (i < 4096) bar[i] = 0u;
  if (i < 8) scal[i] = 0.f;
}

// ------------------------------ persistent loop ----------------------------
struct LoopP {
  const f16 *preT, *hs, *eys, *w0, *w1, *wdec;
  const float *bs0, *bs1;
  const int* hlens;
  f16 *dec, *att, *z0seq, *zout;
  unsigned* bar;
};

__global__ void __launch_bounds__(256, 2) k_loop(LoopP p) {
  __shared__ __align__(16) f16 xs[2][32 * 520];  // 2 staging tiles, 66560 B
  __shared__ float gacc[2176];                   // gate partials / decF
  __shared__ float cbuf[256];                    // c-state slice / att reduce

  const int bid = blockIdx.x, tid = threadIdx.x;
  const int wid = tid >> 6, lane = tid & 63, lr = lane & 15, lq = lane >> 4;
  cbuf[tid] = 0.f;
  __syncthreads();

  // stage one 32x512 f16 tile into dst (row stride 520)
  auto stage = [&](f16* dst, const f16* src, long rs, bool atomic) {
    for (int idx = tid; idx < 4096; idx += 256) {
      int r = idx >> 7, c = idx & 127;
      const void* sp = (const void*)(src + (long)r * rs + c * 4);
      unsigned long long v = atomic ? aload64(sp) : *(const unsigned long long*)sp;
      *(unsigned long long*)(dst + r * 520 + c * 4) = v;
    }
  };

  if (bid < NG0) {
    // ===== role g0: 16 gate rows (4 hidden x 4 gates), K=2560 4-way split ==
    const int par = wid;                         // K-chunk residue mod 4
    const f16* wb = p.w0 + (long)((lr >> 2) * 1024 + bid * 4 + (lr & 3)) * 2560 + lq * 8;
    f16x8 wr[20];
#pragma unroll
    for (int r = 0; r < 20; ++r) {
      const int c = (r < 16) ? ((r >> 2) * 16 + (r & 3) * 4 + par)
                             : (64 + (r - 16) * 4 + par);
      wr[r] = *(const f16x8*)(wb + c * 32);
    }
#pragma unroll
    for (int r = 0; r < 20; ++r) asm volatile("" : "+v"(wr[r]));  // pin in regs
    const bool decduty = (bid < 20);
    const int a0 = bid * 16;
    const f16* wdrow = p.wdec + (long)(a0 + lr) * ND + lq * 8;
    const f16* a00 = xs[0] + lr * 520 + lq * 8;
    const f16* a01 = a00 + 16 * 520;
    const f16* a10 = xs[1] + lr * 520 + lq * 8;
    const f16* a11 = a10 + 16 * 520;
    const float* bs = p.bs0;

    // prologue: eys(0) into both tiles
    stage(xs[0], p.eys, ND, false);
    stage(xs[1], p.eys + 512, ND, false);
    __syncthreads();

    for (int s = 0; s < NL; ++s) {
      f32x4 acc0 = (f32x4){0.f, 0.f, 0.f, 0.f};
      f32x4 acc1 = (f32x4){0.f, 0.f, 0.f, 0.f};
      // ---- Phase A1: ey (prefetched) ----
#pragma unroll
      for (int j = 0; j < 4; ++j) {
        const int co = (4 * j + par) * 32;
        acc0 = __builtin_amdgcn_mfma_f32_16x16x32_f16(*(const f16x8*)(a00 + co), wr[j], acc0, 0, 0, 0);
        acc1 = __builtin_amdgcn_mfma_f32_16x16x32_f16(*(const f16x8*)(a01 + co), wr[j], acc1, 0, 0, 0);
      }
#pragma unroll
      for (int j = 0; j < 4; ++j) {
        const int co = (4 * j + par) * 32;
        acc0 = __builtin_amdgcn_mfma_f32_16x16x32_f16(*(const f16x8*)(a10 + co), wr[4 + j], acc0, 0, 0, 0);
        acc1 = __builtin_amdgcn_mfma_f32_16x16x32_f16(*(const f16x8*)(a11 + co), wr[4 + j], acc1, 0, 0, 0);
      }
      __syncthreads();
      // ---- Phase A2: z0prev (zero at s=0, skip) ----
      if (s > 0) {
        waitflag(p.bar, F_SZ0 + (bid & 15), (unsigned)s);
        stage(xs[0], p.z0seq + (long)(s - 1) * (NB * ND), ND, true);
        stage(xs[1], p.z0seq + (long)(s - 1) * (NB * ND) + 512, ND, true);
        __syncthreads();
#pragma unroll
        for (int j = 0; j < 4; ++j) {
          const int co = (4 * j + par) * 32;
          acc0 = __builtin_amdgcn_mfma_f32_16x16x32_f16(*(const f16x8*)(a00 + co), wr[8 + j], acc0, 0, 0, 0);
          acc1 = __builtin_amdgcn_mfma_f32_16x16x32_f16(*(const f16x8*)(a01 + co), wr[8 + j], acc1, 0, 0, 0);
        }
#pragma unroll
        for (int j = 0; j < 4; ++j) {
          const int co = (4 * j + par) * 32;
          acc0 = __builtin_amdgcn_mfma_f32_16x16x32_f16(*(const f16x8*)(a10 + co), wr[12 + j], acc0, 0, 0, 0);
          acc1 = __builtin_amdgcn_mfma_f32_16x16x32_f16(*(const f16x8*)(a11 + co), wr[12 + j], acc1, 0, 0, 0);
        }
        __syncthreads();
      }
      // ---- Phase B: att part (K 2048:2560) + finalize z0/c0 ----
      waitflag(p.bar, F_SATT + (bid & 15), (unsigned)(s + 1));
      stage(xs[0], p.att, NE, true);
      __syncthreads();
#pragma unroll
      for (int j = 0; j < 4; ++j) {
        const int co = (4 * j + par) * 32;
        acc0 = __builtin_amdgcn_mfma_f32_16x16x32_f16(*(const f16x8*)(a00 + co), wr[16 + j], acc0, 0, 0, 0);
        acc1 = __builtin_amdgcn_mfma_f32_16x16x32_f16(*(const f16x8*)(a01 + co), wr[16 + j], acc1, 0, 0, 0);
      }
#pragma unroll
      for (int reg = 0; reg < 4; ++reg) {
        gacc[par * 544 + (lq * 4 + reg) * 17 + lr]      = acc0[reg];
        gacc[par * 544 + (16 + lq * 4 + reg) * 17 + lr] = acc1[reg];
      }
      __syncthreads();
      if (tid < 64) {
        const int b = tid & 31, q = tid >> 5;   // q=0 -> hh 0,1 ; q=1 -> hh 2,3
        float z[2];
#pragma unroll
        for (int u = 0; u < 2; ++u) {
          const int hh = q * 2 + u;
          float gi = 0.f, gf = 0.f, gv = 0.f, go = 0.f;
#pragma unroll
          for (int pp = 0; pp < 4; ++pp) {
            const float* gp = gacc + pp * 544 + b * 17;
            gi += gp[hh]; gf += gp[4 + hh]; gv += gp[8 + hh]; go += gp[12 + hh];
          }
          const int hb = bid * 4 + hh;
          gi += bs[hb]; gf += bs[1024 + hb]; gv += bs[2048 + hb]; go += bs[3072 + hb];
          float cn = sigf(gf) * cbuf[b * 4 + hh] + sigf(gi) * tanhf_fast(gv);
          cbuf[b * 4 + hh] = cn;
          z[u] = sigf(go) * tanhf_fast(cn);
        }
        astore32((unsigned*)p.z0seq + ((long)s * (NB * ND) + b * ND + bid * 4) / 2 + q,
                 pack2(z[0], z[1]));
      }
      __syncthreads();
      if (tid == 0)
        sigstep(p.bar, S_SZ0 + (bid & 15), 16u * (s + 1), R_SZ0, 16u * (s + 1),
                F_SZ0, 16, (unsigned)(s + 1));
      // ---- Phase C: dec(s+1) on blocks 0..19 ----
      if (decduty) {
        waitflag(p.bar, F_SZ0 + (bid & 15), (unsigned)(s + 1));
        stage(xs[0], p.z0seq + (long)s * (NB * ND), ND, true);
        stage(xs[1], p.z0seq + (long)s * (NB * ND) + 512, ND, true);
        __syncthreads();
        f32x4 dacc = (f32x4){0.f, 0.f, 0.f, 0.f};
        if (wid < 2) {
#pragma unroll
          for (int kt = 0; kt < 2; ++kt) {
            const f16* ap2 = xs[kt] + (wid * 16 + lr) * 520 + lq * 8;
            const f16* wk = wdrow + kt * 512;
#pragma unroll
            for (int kk = 0; kk < 512; kk += 32)
              dacc = __builtin_amdgcn_mfma_f32_16x16x32_f16(
                  *(const f16x8*)(ap2 + kk), *(const f16x8*)(wk + kk), dacc, 0, 0, 0);
          }
        }
        __syncthreads();
        if (wid < 2) {
#pragma unroll
          for (int reg = 0; reg < 4; ++reg)
            gacc[(wid * 16 + lq * 4 + reg) * 33 + lr] = tanhf_fast(dacc[reg]);
        }
        __syncthreads();
        {
          const int b = tid & 31, j = tid >> 5;  // j 0..7 covers 16 cols
          astore32((unsigned*)p.dec + (b * NA + a0) / 2 + j,
                   pack2(gacc[b * 33 + 2 * j], gacc[b * 33 + 2 * j + 1]));
        }
        __syncthreads();
        if (tid == 0)
          sigstep(p.bar, S_SDEC + (bid & 3), 5u * (s + 1), R_SDEC, 4u * (s + 1),
                  F_SDEC, 8, (unsigned)(s + 1));
      }
      // prefetch eys(s+1)
      if (s + 1 < NL) {
        stage(xs[0], p.eys + (long)(s + 1) * (NB * ND), ND, false);
        stage(xs[1], p.eys + (long)(s + 1) * (NB * ND) + 512, ND, false);
      }
      __syncthreads();
    }
  } else if (bid < NG0 + NG1) {
    // ===== role g1: 32 gate rows (8 hidden x 4 gates), K=2048 2-way split ==
    const int g1i = bid - NG0;
    const int rt = wid & 1, par = wid >> 1;      // rt: N-row tile, par: K residue
    const int rrow = rt * 16 + lr;
    const f16* wb = p.w1 + (long)((rrow >> 3) * 1024 + g1i * 8 + (rrow & 7)) * 2048 + lq * 8;
    f16x8 wr[32];
#pragma unroll
    for (int r = 0; r < 32; ++r) {
      const int c = (r < 16) ? ((r >> 3) * 16 + (r & 7) * 2 + par)
                             : (32 + ((r - 16) >> 3) * 16 + ((r - 16) & 7) * 2 + par);
      wr[r] = *(const f16x8*)(wb + c * 32);
    }
#pragma unroll
    for (int r = 0; r < 32; ++r) asm volatile("" : "+v"(wr[r]));  // pin in regs
    const f16* a00 = xs[0] + lr * 520 + lq * 8;
    const f16* a01 = a00 + 16 * 520;
    const f16* a10 = xs[1] + lr * 520 + lq * 8;
    const f16* a11 = a10 + 16 * 520;
    const float* bs = p.bs1;
    const int h0 = g1i * 8;

    for (int s = 0; s < NL; ++s) {
      f32x4 acc0 = (f32x4){0.f, 0.f, 0.f, 0.f};
      f32x4 acc1 = (f32x4){0.f, 0.f, 0.f, 0.f};
      // ---- z1prev part (zero at s=0, skip) ----
      if (s > 0) {
        waitflag(p.bar, F_SZ1 + (g1i & 7), (unsigned)s);
        stage(xs[0], p.zout + (long)(s - 1) * (NB * ND), ND, true);
        stage(xs[1], p.zout + (long)(s - 1) * (NB * ND) + 512, ND, true);
        __syncthreads();
#pragma unroll
        for (int j = 0; j < 8; ++j) {
          const int co = (2 * j + par) * 32;
          acc0 = __builtin_amdgcn_mfma_f32_16x16x32_f16(*(const f16x8*)(a00 + co), wr[16 + j], acc0, 0, 0, 0);
          acc1 = __builtin_amdgcn_mfma_f32_16x16x32_f16(*(const f16x8*)(a01 + co), wr[16 + j], acc1, 0, 0, 0);
        }
#pragma unroll
        for (int j = 0; j < 8; ++j) {
          const int co = (2 * j + par) * 32;
          acc0 = __builtin_amdgcn_mfma_f32_16x16x32_f16(*(const f16x8*)(a10 + co), wr[24 + j], acc0, 0, 0, 0);
          acc1 = __builtin_amdgcn_mfma_f32_16x16x32_f16(*(const f16x8*)(a11 + co), wr[24 + j], acc1, 0, 0, 0);
        }
        __syncthreads();
      }
      // ---- z0 part + finalize z1/c1 ----
      waitflag(p.bar, F_SZ0 + (bid & 15), (unsigned)(s + 1));
      stage(xs[0], p.z0seq + (long)s * (NB * ND), ND, true);
      stage(xs[1], p.z0seq + (long)s * (NB * ND) + 512, ND, true);
      __syncthreads();
#pragma unroll
      for (int j = 0; j < 8; ++j) {
        const int co = (2 * j + par) * 32;
        acc0 = __builtin_amdgcn_mfma_f32_16x16x32_f16(*(const f16x8*)(a00 + co), wr[j], acc0, 0, 0, 0);
        acc1 = __builtin_amdgcn_mfma_f32_16x16x32_f16(*(const f16x8*)(a01 + co), wr[j], acc1, 0, 0, 0);
      }
#pragma unroll
      for (int j = 0; j < 8; ++j) {
        const int co = (2 * j + par) * 32;
        acc0 = __builtin_amdgcn_mfma_f32_16x16x32_f16(*(const f16x8*)(a10 + co), wr[8 + j], acc0, 0, 0, 0);
        acc1 = __builtin_amdgcn_mfma_f32_16x16x32_f16(*(const f16x8*)(a11 + co), wr[8 + j], acc1, 0, 0, 0);
      }
#pragma unroll
      for (int reg = 0; reg < 4; ++reg) {
        gacc[par * 1056 + (lq * 4 + reg) * 33 + rrow]      = acc0[reg];
        gacc[par * 1056 + (16 + lq * 4 + reg) * 33 + rrow] = acc1[reg];
      }
      __syncthreads();
      if (tid < 128) {
        const int b = tid & 31, hp = tid >> 5;
        float z[2];
#pragma unroll
        for (int u = 0; u < 2; ++u) {
          const int hh = hp * 2 + u;
          float gi = gacc[b * 33 + hh]      + gacc[1056 + b * 33 + hh]      + bs[h0 + hh];
          float gf = gacc[b * 33 + 8 + hh]  + gacc[1056 + b * 33 + 8 + hh]  + bs[1024 + h0 + hh];
          float gv = gacc[b * 33 + 16 + hh] + gacc[1056 + b * 33 + 16 + hh] + bs[2048 + h0 + hh];
          float go = gacc[b * 33 + 24 + hh] + gacc[1056 + b * 33 + 24 + hh] + bs[3072 + h0 + hh];
          float cn = sigf(gf) * cbuf[b * 8 + hh] + sigf(gi) * tanhf_fast(gv);
          cbuf[b * 8 + hh] = cn;
          z[u] = sigf(go) * tanhf_fast(cn);
        }
        astore32((unsigned*)p.zout + ((long)s * (NB * ND) + b * ND + h0) / 2 + hp,
                 pack2(z[0], z[1]));
      }
      __syncthreads();
      if (tid == 0)
        sigstep(p.bar, S_SZ1 + (g1i & 7), 16u * (s + 1), R_SZ1, 8u * (s + 1),
                F_SZ1, 8, (unsigned)(s + 1));
    }
  } else {
    // ================= role attention (one block per batch b) ==============
    const int b = bid - (NG0 + NG1);
    const int hlen = p.hlens[b];
    float* epart = (float*)xs;             // [4][512]
    float* apart = (float*)xs + 2048;      // [4][512]
    float* wL    = (float*)xs + 4096;      // [512]
    float* decF  = gacc;                   // [320]
    float* red   = cbuf;                   // [4]
    const f16* pe  = p.preT + (long)b * NA * 512;   // [a][t]
    const f16* ph  = p.hs   + (long)b * 512 * 512;  // [t][e]

    for (int s = 0; s < NL; ++s) {
      if (s > 0) waitflag(p.bar, F_SDEC + (b & 7), (unsigned)s);  // dec(s) ready
      if (tid < 80) {
        PU64 v; v.u = aload64((const unsigned long long*)p.dec + b * 80 + tid);
#pragma unroll
        for (int i = 0; i < 4; ++i) decF[tid * 4 + i] = (float)v.h[i];
      }
      __syncthreads();
      // e partials: wave w covers a in [80w,80w+80); lane covers t-group 8*lane
      {
        float ea[8] = {0.f,0.f,0.f,0.f,0.f,0.f,0.f,0.f};
#pragma unroll 8
        for (int aa = 0; aa < 80; ++aa) {
          const int a = wid * 80 + aa;
          f16x8 pv = *(const f16x8*)(pe + (long)a * 512 + lane * 8);
          const float d = decF[a];
#pragma unroll
          for (int j = 0; j < 8; ++j) ea[j] += (float)pv[j] * d;
        }
#pragma unroll
        for (int j = 0; j < 8; ++j) epart[wid * 512 + lane * 8 + j] = ea[j];
      }
      __syncthreads();
      const int t0 = 2 * tid, t1 = 2 * tid + 1;
      float e0 = (epart[t0] + epart[512 + t0] + epart[1024 + t0] + epart[1536 + t0]) * 2.0f;
      float e1 = (epart[t1] + epart[512 + t1] + epart[1024 + t1] + epart[1536 + t1]) * 2.0f;
      float m = fmaxf((t0 < hlen) ? e0 : -3e38f, (t1 < hlen) ? e1 : -3e38f);
#pragma unroll
      for (int off = 1; off < 64; off <<= 1) m = fmaxf(m, __shfl_xor(m, off));
      if (lane == 0) red[wid] = m;
      __syncthreads();
      const float M = fmaxf(fmaxf(red[0], red[1]), fmaxf(red[2], red[3]));
      float w0 = (t0 < hlen) ? __expf(e0 - M) : 0.f;
      float w1 = (t1 < hlen) ? __expf(e1 - M) : 0.f;
      wL[t0] = w0; wL[t1] = w1;
      float sm = w0 + w1;
#pragma unroll
      for (int off = 1; off < 64; off <<= 1) sm += __shfl_xor(sm, off);
      __syncthreads();               // wL visible + red reusable
      if (lane == 0) red[wid] = sm;
      __syncthreads();
      const float inv = 1.0f / (red[0] + red[1] + red[2] + red[3]);
      // att_c partials: wave w covers t in [128w,128w+128); lane covers 8 e-cols
      {
        float ac[8] = {0.f,0.f,0.f,0.f,0.f,0.f,0.f,0.f};
#pragma unroll 8
        for (int tt = 0; tt < 128; ++tt) {
          const int t = wid * 128 + tt;
          f16x8 hv = *(const f16x8*)(ph + (long)t * 512 + lane * 8);
          const float w = wL[t];
#pragma unroll
          for (int j = 0; j < 8; ++j) ac[j] += (float)hv[j] * w;
        }
#pragma unroll
        for (int j = 0; j < 8; ++j) apart[wid * 512 + lane * 8 + j] = ac[j];
      }
      __syncthreads();
      {
        float s0 = apart[t0] + apart[512 + t0] + apart[1024 + t0] + apart[1536 + t0];
        float s1 = apart[t1] + apart[512 + t1] + apart[1024 + t1] + apart[1536 + t1];
        astore32((unsigned*)p.att + b * 256 + tid, pack2(s0 * inv, s1 * inv));
      }
      __syncthreads();
      if (tid == 0)
        sigstep(p.bar, S_SATT + (b & 3), 8u * (s + 1), R_SATT, 4u * (s + 1),
                F_SATT, 16, (unsigned)(s + 1));
    }
  }
}

// ------------------------- logits GEMM + fused CE stats --------------------
__global__ void __launch_bounds__(256) k_lgemm(const f16* __restrict__ z, const f16* __restrict__ wout,
                                               const float* __restrict__ bout, float4* __restrict__ part) {
  const int mb = blockIdx.x, nb = blockIdx.y;
  const int wid = threadIdx.x >> 6, lane = threadIdx.x & 63;
  const int lr = lane & 15, lq = lane >> 4;
  const int m0 = mb * 32;
  const int n0 = nb * 512 + wid * 128;
  const f16* arow0 = z + (long)(m0 + lr) * 1024 + lq * 8;
  const f16* arow1 = arow0 + (long)16 * 1024;
  const f16* bp[8];
  int cols[8];
#pragma unroll
  for (int nt = 0; nt < 8; ++nt) {
    int n = n0 + nt * 16 + lr;
    cols[nt] = n;
    int nc = (n < NO) ? n : (NO - 1);
    bp[nt] = wout + (long)nc * 1024 + lq * 8;
  }
  f32x4 acc[16];
#pragma unroll
  for (int i = 0; i < 16; ++i) acc[i] = (f32x4){0.f, 0.f, 0.f, 0.f};
  for (int kk = 0; kk < 1024; kk += 32) {
    f16x8 a0v = *(const f16x8*)(arow0 + kk);
    f16x8 a1v = *(const f16x8*)(arow1 + kk);
#pragma unroll
    for (int nt = 0; nt < 8; ++nt) {
      f16x8 bv = *(const f16x8*)(bp[nt] + kk);
      acc[nt]     = __builtin_amdgcn_mfma_f32_16x16x32_f16(a0v, bv, acc[nt], 0, 0, 0);
      acc[8 + nt] = __builtin_amdgcn_mfma_f32_16x16x32_f16(a1v, bv, acc[8 + nt], 0, 0, 0);
    }
  }
  float bias[8];
#pragma unroll
  for (int nt = 0; nt < 8; ++nt) bias[nt] = (cols[nt] < NO) ? bout[cols[nt]] : 0.f;
  const int chunk = nb * 4 + wid;
#pragma unroll
  for (int mt = 0; mt < 2; ++mt) {
#pragma unroll
    for (int reg = 0; reg < 4; ++reg) {
      float vals[8];
      float mx = -1e30f, av = -1e30f; int ai = 0;
#pragma unroll
      for (int nt = 0; nt < 8; ++nt) {
        float v = (cols[nt] < NO) ? (acc[mt * 8 + nt][reg] + bias[nt]) : -1e30f;
        vals[nt] = v;
        mx = fmaxf(mx, v);
        if (v > av) { av = v; ai = cols[nt]; }
      }
      float sum = 0.f;
#pragma unroll
      for (int nt = 0; nt < 8; ++nt) sum += (vals[nt] > -9e29f) ? __expf(vals[nt] - mx) : 0.f;
#pragma unroll
      for (int off = 1; off < 16; off <<= 1) {
        float mo = __shfl_xor(mx, off);
        float so = __shfl_xor(sum, off);
        float avo = __shfl_xor(av, off);
        int aio = __shfl_xor(ai, off);
        float nm = fmaxf(mx, mo);
        float e1 = (mx > -9e29f) ? __expf(mx - nm) : 0.f;
        float e2 = (mo > -9e29f) ? __expf(mo - nm) : 0.f;
        sum = sum * e1 + so * e2;
        mx = nm;
        if (avo > av || (avo == av && aio < ai)) { av = avo; ai = aio; }
      }
      if (lr == 0) {
        int rowg = m0 + mt * 16 + lq * 4 + reg;
        float4 q; q.x = mx; q.y = sum; q.z = av; q.w = __int_as_float(ai);
        part[(long)rowg * 80 + chunk] = q;
      }
    }
  }
}

__global__ void k_tl(const f16* __restrict__ z, const f16* __restrict__ wout,
                     const float* __restrict__ bout, const int* __restrict__ ys, float* __restrict__ tl) {
  const int tok = blockIdx.x * 4 + (threadIdx.x >> 6);
  const int lane = threadIdx.x & 63;
  if (tok >= NTOK) return;
  const int s = tok >> 5, b = tok & 31;
  const int tgt = (s < 128) ? ys[b * 128 + s] : SOS_ID;
  const f16x8* zp = (const f16x8*)(z + (long)tok * 1024);
  const f16x8* wp = (const f16x8*)(wout + (long)tgt * 1024);
  float acc = 0.f;
  acc = dot8(zp[lane], wp[lane], acc);
  acc = dot8(zp[64 + lane], wp[64 + lane], acc);
#pragma unroll
  for (int off = 32; off > 0; off >>= 1) acc += __shfl_xor(acc, off);
  if (lane == 0) tl[tok] = acc + bout[tgt];
}

__global__ void k_ce(const float4* __restrict__ part, const float* __restrict__ tl,
                     const int* __restrict__ ys, float* scal) {
  const int m = blockIdx.x * 256 + threadIdx.x;
  float nll = 0.f, okf = 0.f;
  if (m < NTOK) {
    float M = -1e30f, S = 0.f, av = -1e30f; int ai = 0;
    for (int c = 0; c < 80; ++c) {
      float4 q = part[(long)m * 80 + c];
      float qm = q.x, qs = q.y, qa = q.z; int qi = __float_as_int(q.w);
      float nm = fmaxf(M, qm);
      float e1 = (M > -9e29f) ? __expf(M - nm) : 0.f;
      float e2 = (qm > -9e29f) ? __expf(qm - nm) : 0.f;
      S = S * e1 + qs * e2; M = nm;
      if (qa > av || (qa == av && qi < ai)) { av = qa; ai = qi; }
    }
    float lse = M + __logf(S);
    int s = m >> 5, b = m & 31;
    int tgt = (s < 128) ? ys[b * 128 + s] : SOS_ID;
    nll = lse - tl[m];
    okf = (ai == tgt) ? 1.f : 0.f;
  }
  __shared__ float r1[256], r2[256];
  r1[threadIdx.x] = nll; r2[threadIdx.x] = okf; __syncthreads();
  for (int st = 128; st > 0; st >>= 1) {
    if (threadIdx.x < st) { r1[threadIdx.x] += r1[threadIdx.x + st]; r2[threadIdx.x] += r2[threadIdx.x + st]; }
    __syncthreads();
  }
  if (threadIdx.x == 0) { atomicAdd(&scal[0], r1[0]); atomicAdd(&scal[1], r2[0]); }
}

__global__ void k_final(const float* scal, float* out) {
  if (threadIdx.x == 0) {
    float loss = scal[0] * (128.f / 4128.f);
    out[0] = loss;
    out[1] = scal[1] * (1.f / 4128.f);
    out[2] = expf(loss / 32.f);
  }
}

// --------------------------------- launch ----------------------------------
extern "C" void kernel_launch(void* const* d_in, const int* in_sizes, int n_in,
                              void* d_out, int out_size, void* d_ws, size_t ws_size,
                              hipStream_t stream) {
  const float* hs_pad = (const float*)d_in[0];
  const int* hlens    = (const int*)d_in[1];
  const int* ys_pad   = (const int*)d_in[2];
  const float* embed  = (const float*)d_in[3];
  const float* Wenc   = (const float*)d_in[4];
  const float* benc   = (const float*)d_in[5];
  const float* Wdec   = (const float*)d_in[6];
  const float* Wih0   = (const float*)d_in[7];
  const float* Whh0   = (const float*)d_in[8];
  const float* bih0   = (const float*)d_in[9];
  const float* bhh0   = (const float*)d_in[10];
  const float* Wih1   = (const float*)d_in[11];
  const float* Whh1   = (const float*)d_in[12];
  const float* bih1   = (const float*)d_in[13];
  const float* bhh1   = (const float*)d_in[14];
  const float* Wout   = (const float*)d_in[15];
  const float* bout   = (const float*)d_in[16];
  float* out = (float*)d_out;
  (void)in_sizes; (void)n_in; (void)out_size; (void)ws_size;

  char* ws = (char*)d_ws;
  size_t off = 0;
  auto alloc = [&](size_t bytes) -> char* {
    char* pp = ws + off;
    off = (off + bytes + 255) & ~(size_t)255;
    return pp;
  };
  f16* hs16    = (f16*)alloc((size_t)NB * NTT * NE * 2);
  f16* preT    = (f16*)alloc((size_t)NB * NA * NTT * 2);
  f16* eys16   = (f16*)alloc((size_t)NL * NB * ND * 2);
  f16* w0cat   = (f16*)alloc((size_t)4096 * 2560 * 2);
  f16* w1cat   = (f16*)alloc((size_t)4096 * 2048 * 2);
  f16* wdec16  = (f16*)alloc((size_t)NA * ND * 2);
  f16* wenc16  = (f16*)alloc((size_t)NA * NE * 2);
  f16* wout16  = (f16*)alloc((size_t)NO * ND * 2);
  f16* zout    = (f16*)alloc((size_t)NTOK * ND * 2);
  f16* z0seq   = (f16*)alloc((size_t)NL * NB * ND * 2);
  f16* dec16   = (f16*)alloc((size_t)NB * NA * 2);
  f16* att16   = (f16*)alloc((size_t)NB * NE * 2);
  float* bs0   = (float*)alloc(4096 * 4);
  float* bs1   = (float*)alloc(4096 * 4);
  float* tl    = (float*)alloc((size_t)NTOK * 4);
  float4* part = (float4*)alloc((size_t)NTOK * 80 * 16);
  float* scal  = (float*)alloc(256);
  unsigned* bar = (unsigned*)alloc(16384);

  k_cvt<<<dim3(2048), dim3(256), 0, stream>>>(hs_pad, hs16, (long)NB * NTT * NE);
  k_cvt<<<dim3(256), dim3(256), 0, stream>>>(Wdec, wdec16, (long)NA * ND);
  k_cvt<<<dim3(128), dim3(256), 0, stream>>>(Wenc, wenc16, (long)NA * NE);
  k_cvt<<<dim3(2048), dim3(256), 0, stream>>>(Wout, wout16, (long)NO * ND);
  k_w0cat<<<dim3(10, 4096), dim3(256), 0, stream>>>(Wih0, Whh0, w0cat);
  k_w1cat<<<dim3(8, 4096), dim3(256), 0, stream>>>(Wih1, Whh1, w1cat);
  k_eys<<<dim3(4, NL * NB), dim3(256), 0, stream>>>(ys_pad, embed, eys16);
  k_pre<<<dim3(512), dim3(256), 0, stream>>>(hs16, wenc16, benc, preT);
  k_bias<<<dim3(16), dim3(256), 0, stream>>>(bih0, bhh0, bih1, bhh1, bs0, bs1);
  k_zero<<<dim3(128), dim3(256), 0, stream>>>(dec16, scal, bar);

  LoopP lp;
  lp.preT = preT; lp.hs = hs16; lp.eys = eys16; lp.w0 = w0cat; lp.w1 = w1cat; lp.wdec = wdec16;
  lp.bs0 = bs0; lp.bs1 = bs1; lp.hlens = hlens;
  lp.dec = dec16; lp.att = att16; lp.z0seq = z0seq; lp.zout = zout; lp.bar = bar;
  k_loop<<<dim3(GRID_LOOP), dim3(256), 0, stream>>>(lp);

  k_tl<<<dim3(NTOK / 4), dim3(256), 0, stream>>>(zout, wout16, bout, ys_pad, tl);
  k_lgemm<<<dim3(129, 20), dim3(256), 0, stream>>>(zout, wout16, bout, part);
  k_ce<<<dim3(17), dim3(256), 0, stream>>>(part, tl, ys_pad, scal);
  k_final<<<dim3(1), dim3(64), 0, stream>>>(scal, out);
}

// Round 4
// 6673.265 us; speedup vs baseline: 1.9545x; 1.0051x over previous
//
#include <hip/hip_runtime.h>
#include <hip/hip_fp16.h>
#include <math.h>

// ---------------------------------------------------------------------------
// Decoder (ESPnet AttDot + 2x LSTMCell + CE) on gfx950.
// R7 -> R8: two-hop critical cycle + relaxed signals.
//  R7: 42us/step, idle counters -> hop cost dominated. Changes:
//  1) RELEASE fetch_add on signals emitted L2-writeback (buffer_wbl2) on
//     gfx950 (non-coherent per-XCD L2). All data stores are sc1 agent
//     atomics and __syncthreads drains vmcnt per wave, so after the
//     block-wide sync all stores are at L3 => RELAXED signal ops suffice.
//  2) dec fused into att blocks: each att block stages z0[b] (2KB), computes
//     dec[b]=tanh(z0[b].WdecT) in-block (Wdec L2-resident, 327K MAC), writes
//     to LDS decF. Removes dec-duty role, sdec signal, p.dec buffer, and one
//     full hop: cycle is now sz0 -> att(+dec) -> satt -> g0 PhaseB -> sz0.
//  3) att_c loop bounded by hlen.
// ---------------------------------------------------------------------------

typedef _Float16 f16;
typedef _Float16 f16x2 __attribute__((ext_vector_type(2)));
typedef _Float16 f16x4 __attribute__((ext_vector_type(4)));
typedef _Float16 f16x8 __attribute__((ext_vector_type(8)));
typedef float f32x4 __attribute__((ext_vector_type(4)));

#define SOS_ID 9999
#define NB 32
#define NTT 512
#define NE 512
#define ND 1024
#define NA 320
#define NO 10000
#define NL 129
#define NTOK (NL*NB)
#define NG0 256
#define NG1 128
#define GRID_LOOP 416   // 256 g0 + 128 g1 + 32 att

// signal slot indices (unsigned slots, stride 32 = one 128B line each)
#define S_SZ0  0
#define R_SZ0  16
#define S_SZ1  17
#define R_SZ1  25
#define S_SATT 26
#define R_SATT 30
#define F_SZ0  64
#define F_SZ1  80
#define F_SATT 88

union PU32 { unsigned u; f16x2 h; };
union PU64 { unsigned long long u; f16x4 h; unsigned w[2]; };

__device__ __forceinline__ float fdot2f(f16x2 a, f16x2 b, float c) {
#if __has_builtin(__builtin_amdgcn_fdot2)
  return __builtin_amdgcn_fdot2(a, b, c, false);
#else
  return c + (float)a[0]*(float)b[0] + (float)a[1]*(float)b[1];
#endif
}
__device__ __forceinline__ float dot8(f16x8 a, f16x8 b, float acc) {
  acc = fdot2f(__builtin_shufflevector(a, a, 0, 1), __builtin_shufflevector(b, b, 0, 1), acc);
  acc = fdot2f(__builtin_shufflevector(a, a, 2, 3), __builtin_shufflevector(b, b, 2, 3), acc);
  acc = fdot2f(__builtin_shufflevector(a, a, 4, 5), __builtin_shufflevector(b, b, 4, 5), acc);
  acc = fdot2f(__builtin_shufflevector(a, a, 6, 7), __builtin_shufflevector(b, b, 6, 7), acc);
  return acc;
}
__device__ __forceinline__ float sigf(float x) { return 1.0f / (1.0f + __expf(-x)); }
__device__ __forceinline__ float tanhf_fast(float x) { return 1.0f - 2.0f / (1.0f + __expf(2.0f * x)); }

__device__ __forceinline__ unsigned long long aload64(const void* p) {
  return __hip_atomic_load((const unsigned long long*)p, __ATOMIC_RELAXED, __HIP_MEMORY_SCOPE_AGENT);
}
__device__ __forceinline__ void astore32(void* p, unsigned v) {
  __hip_atomic_store((unsigned*)p, v, __ATOMIC_RELAXED, __HIP_MEMORY_SCOPE_AGENT);
}
__device__ __forceinline__ unsigned pack2(float a, float b) {
  PU32 u; u.h[0] = (f16)a; u.h[1] = (f16)b; return u.u;
}

// producer-side signal: sub counter -> root counter -> replicated flags.
// All RELAXED: callers invoke from tid 0 after __syncthreads(), which drains
// each wave's vmcnt => all block stores (sc1, L2-bypass) are at L3 already.
__device__ __forceinline__ void sigstep(unsigned* bar, int sub, unsigned subtgt,
                                        int root, unsigned roottgt,
                                        int flag0, int nrep, unsigned val) {
  asm volatile("s_waitcnt vmcnt(0)" ::: "memory");
  unsigned old = __hip_atomic_fetch_add(&bar[sub * 32], 1u, __ATOMIC_RELAXED, __HIP_MEMORY_SCOPE_AGENT);
  if (old + 1u == subtgt) {
    unsigned r = __hip_atomic_fetch_add(&bar[root * 32], 1u, __ATOMIC_RELAXED, __HIP_MEMORY_SCOPE_AGENT);
    if (r + 1u == roottgt) {
      for (int i = 0; i < nrep; ++i)
        __hip_atomic_store(&bar[(flag0 + i) * 32], val, __ATOMIC_RELAXED, __HIP_MEMORY_SCOPE_AGENT);
    }
  }
}
// consumer-side wait on a replicated flag
__device__ __forceinline__ void waitflag(unsigned* bar, int slot, unsigned val) {
  if (threadIdx.x == 0) {
    while (__hip_atomic_load(&bar[slot * 32], __ATOMIC_RELAXED, __HIP_MEMORY_SCOPE_AGENT) < val)
      __builtin_amdgcn_s_sleep(1);
  }
  __syncthreads();
  asm volatile("" ::: "memory");
}

// ------------------------------ prep kernels -------------------------------
__global__ void k_cvt(const float* __restrict__ s, f16* __restrict__ d, long n) {
  long i = (long)blockIdx.x * 256 + threadIdx.x;
  long st = (long)gridDim.x * 256;
  for (; i < n; i += st) d[i] = (f16)s[i];
}
// w0cat cols: [0:1024)=Wih0 ey part, [1024:2048)=Whh0 (z0prev), [2048:2560)=Wih0 att part
__global__ void k_w0cat(const float* __restrict__ wih, const float* __restrict__ whh, f16* __restrict__ dst) {
  int j = blockIdx.y; int k = blockIdx.x * 256 + threadIdx.x;
  float v;
  if (k < 1024)      v = wih[(long)j * 1536 + k];
  else if (k < 2048) v = whh[(long)j * 1024 + (k - 1024)];
  else               v = wih[(long)j * 1536 + 1024 + (k - 2048)];
  dst[(long)j * 2560 + k] = (f16)v;
}
// w1cat cols: [0:1024)=Wih1 (z0), [1024:2048)=Whh1 (z1prev)
__global__ void k_w1cat(const float* __restrict__ wih, const float* __restrict__ whh, f16* __restrict__ dst) {
  int j = blockIdx.y; int k = blockIdx.x * 256 + threadIdx.x;
  float v = (k < 1024) ? wih[(long)j * 1024 + k] : whh[(long)j * 1024 + (k - 1024)];
  dst[(long)j * 2048 + k] = (f16)v;
}
__global__ void k_eys(const int* __restrict__ ys, const float* __restrict__ emb, f16* __restrict__ eys) {
  int sb = blockIdx.y; int k = blockIdx.x * 256 + threadIdx.x;
  int s = sb >> 5, b = sb & 31;
  int tok = (s == 0) ? SOS_ID : ys[b * 128 + (s - 1)];
  eys[(long)sb * 1024 + k] = (f16)emb[(long)tok * 1024 + k];
}
// preT[b][a][t] = tanh(hs[b][t][:].wenc[a][:] + benc[a])  (t-contiguous)
__global__ void k_pre(const f16* __restrict__ hs, const f16* __restrict__ wenc,
                      const float* __restrict__ benc, f16* __restrict__ preT) {
  const int row0 = blockIdx.x * 32;
  for (int idx = threadIdx.x; idx < 32 * NA; idx += 256) {
    int r = row0 + idx / NA, a = idx % NA;
    const f16x8* hp = (const f16x8*)(hs + (long)r * NE);
    const f16x8* wp = (const f16x8*)(wenc + (long)a * NE);
    float acc = 0.f;
#pragma unroll 4
    for (int k = 0; k < 64; ++k) acc = dot8(hp[k], wp[k], acc);
    int b = r >> 9, t = r & 511;
    preT[((long)b * NA + a) * 512 + t] = (f16)tanhf_fast(acc + benc[a]);
  }
}
__global__ void k_bias(const float* a0, const float* b0, const float* a1, const float* b1,
                       float* s0, float* s1) {
  int i = blockIdx.x * 256 + threadIdx.x;
  if (i < 4096) { s0[i] = a0[i] + b0[i]; s1[i] = a1[i] + b1[i]; }
}
__global__ void k_zero(float* scal, unsigned* bar) {
  int i = blockIdx.x * 256 + threadIdx.x;
  if (i < 4096) bar[i] = 0u;
  if (i < 8) scal[i] = 0.f;
}

// ------------------------------ persistent loop ----------------------------
struct LoopP {
  const f16 *preT, *hs, *eys, *w0, *w1, *wdec;
  const float *bs0, *bs1;
  const int* hlens;
  f16 *att, *z0seq, *zout;
  unsigned* bar;
};

__global__ void __launch_bounds__(256, 2) k_loop(LoopP p) {
  __shared__ __align__(16) f16 xs[2][32 * 520];  // 2 staging tiles, 66560 B
  __shared__ float gacc[2176];                   // gate partials / decF
  __shared__ float cbuf[256];                    // c-state slice / att reduce

  const int bid = blockIdx.x, tid = threadIdx.x;
  const int wid = tid >> 6, lane = tid & 63, lr = lane & 15, lq = lane >> 4;
  cbuf[tid] = 0.f;
  __syncthreads();

  // stage one 32x512 f16 tile into dst (row stride 520)
  auto stage = [&](f16* dst, const f16* src, long rs, bool atomic) {
    for (int idx = tid; idx < 4096; idx += 256) {
      int r = idx >> 7, c = idx & 127;
      const void* sp = (const void*)(src + (long)r * rs + c * 4);
      unsigned long long v = atomic ? aload64(sp) : *(const unsigned long long*)sp;
      *(unsigned long long*)(dst + r * 520 + c * 4) = v;
    }
  };

  if (bid < NG0) {
    // ===== role g0: 16 gate rows (4 hidden x 4 gates), K=2560 4-way split ==
    const int par = wid;                         // K-chunk residue mod 4
    const f16* wb = p.w0 + (long)((lr >> 2) * 1024 + bid * 4 + (lr & 3)) * 2560 + lq * 8;
    f16x8 wr[20];
#pragma unroll
    for (int r = 0; r < 20; ++r) {
      const int c = (r < 16) ? ((r >> 2) * 16 + (r & 3) * 4 + par)
                             : (64 + (r - 16) * 4 + par);
      wr[r] = *(const f16x8*)(wb + c * 32);
    }
#pragma unroll
    for (int r = 0; r < 20; ++r) asm volatile("" : "+v"(wr[r]));  // pin in regs
    const f16* a00 = xs[0] + lr * 520 + lq * 8;
    const f16* a01 = a00 + 16 * 520;
    const f16* a10 = xs[1] + lr * 520 + lq * 8;
    const f16* a11 = a10 + 16 * 520;
    const float* bs = p.bs0;

    // prologue: eys(0) into both tiles
    stage(xs[0], p.eys, ND, false);
    stage(xs[1], p.eys + 512, ND, false);
    __syncthreads();

    for (int s = 0; s < NL; ++s) {
      f32x4 acc0 = (f32x4){0.f, 0.f, 0.f, 0.f};
      f32x4 acc1 = (f32x4){0.f, 0.f, 0.f, 0.f};
      // ---- Phase A1: ey (prefetched) ----
#pragma unroll
      for (int j = 0; j < 4; ++j) {
        const int co = (4 * j + par) * 32;
        acc0 = __builtin_amdgcn_mfma_f32_16x16x32_f16(*(const f16x8*)(a00 + co), wr[j], acc0, 0, 0, 0);
        acc1 = __builtin_amdgcn_mfma_f32_16x16x32_f16(*(const f16x8*)(a01 + co), wr[j], acc1, 0, 0, 0);
      }
#pragma unroll
      for (int j = 0; j < 4; ++j) {
        const int co = (4 * j + par) * 32;
        acc0 = __builtin_amdgcn_mfma_f32_16x16x32_f16(*(const f16x8*)(a10 + co), wr[4 + j], acc0, 0, 0, 0);
        acc1 = __builtin_amdgcn_mfma_f32_16x16x32_f16(*(const f16x8*)(a11 + co), wr[4 + j], acc1, 0, 0, 0);
      }
      __syncthreads();
      // ---- Phase A2: z0prev (zero at s=0, skip) ----
      if (s > 0) {
        waitflag(p.bar, F_SZ0 + (bid & 15), (unsigned)s);
        stage(xs[0], p.z0seq + (long)(s - 1) * (NB * ND), ND, true);
        stage(xs[1], p.z0seq + (long)(s - 1) * (NB * ND) + 512, ND, true);
        __syncthreads();
#pragma unroll
        for (int j = 0; j < 4; ++j) {
          const int co = (4 * j + par) * 32;
          acc0 = __builtin_amdgcn_mfma_f32_16x16x32_f16(*(const f16x8*)(a00 + co), wr[8 + j], acc0, 0, 0, 0);
          acc1 = __builtin_amdgcn_mfma_f32_16x16x32_f16(*(const f16x8*)(a01 + co), wr[8 + j], acc1, 0, 0, 0);
        }
#pragma unroll
        for (int j = 0; j < 4; ++j) {
          const int co = (4 * j + par) * 32;
          acc0 = __builtin_amdgcn_mfma_f32_16x16x32_f16(*(const f16x8*)(a10 + co), wr[12 + j], acc0, 0, 0, 0);
          acc1 = __builtin_amdgcn_mfma_f32_16x16x32_f16(*(const f16x8*)(a11 + co), wr[12 + j], acc1, 0, 0, 0);
        }
        __syncthreads();
      }
      // ---- Phase B: att part (K 2048:2560) + finalize z0/c0 ----
      waitflag(p.bar, F_SATT + (bid & 15), (unsigned)(s + 1));
      stage(xs[0], p.att, NE, true);
      __syncthreads();
#pragma unroll
      for (int j = 0; j < 4; ++j) {
        const int co = (4 * j + par) * 32;
        acc0 = __builtin_amdgcn_mfma_f32_16x16x32_f16(*(const f16x8*)(a00 + co), wr[16 + j], acc0, 0, 0, 0);
        acc1 = __builtin_amdgcn_mfma_f32_16x16x32_f16(*(const f16x8*)(a01 + co), wr[16 + j], acc1, 0, 0, 0);
      }
#pragma unroll
      for (int reg = 0; reg < 4; ++reg) {
        gacc[par * 544 + (lq * 4 + reg) * 17 + lr]      = acc0[reg];
        gacc[par * 544 + (16 + lq * 4 + reg) * 17 + lr] = acc1[reg];
      }
      __syncthreads();
      if (tid < 64) {
        const int b = tid & 31, q = tid >> 5;   // q=0 -> hh 0,1 ; q=1 -> hh 2,3
        float z[2];
#pragma unroll
        for (int u = 0; u < 2; ++u) {
          const int hh = q * 2 + u;
          float gi = 0.f, gf = 0.f, gv = 0.f, go = 0.f;
#pragma unroll
          for (int pp = 0; pp < 4; ++pp) {
            const float* gp = gacc + pp * 544 + b * 17;
            gi += gp[hh]; gf += gp[4 + hh]; gv += gp[8 + hh]; go += gp[12 + hh];
          }
          const int hb = bid * 4 + hh;
          gi += bs[hb]; gf += bs[1024 + hb]; gv += bs[2048 + hb]; go += bs[3072 + hb];
          float cn = sigf(gf) * cbuf[b * 4 + hh] + sigf(gi) * tanhf_fast(gv);
          cbuf[b * 4 + hh] = cn;
          z[u] = sigf(go) * tanhf_fast(cn);
        }
        astore32((unsigned*)p.z0seq + ((long)s * (NB * ND) + b * ND + bid * 4) / 2 + q,
                 pack2(z[0], z[1]));
      }
      __syncthreads();
      if (tid == 0)
        sigstep(p.bar, S_SZ0 + (bid & 15), 16u * (s + 1), R_SZ0, 16u * (s + 1),
                F_SZ0, 16, (unsigned)(s + 1));
      // ---- Phase C: prefetch eys(s+1) ----
      if (s + 1 < NL) {
        stage(xs[0], p.eys + (long)(s + 1) * (NB * ND), ND, false);
        stage(xs[1], p.eys + (long)(s + 1) * (NB * ND) + 512, ND, false);
      }
      __syncthreads();
    }
  } else if (bid < NG0 + NG1) {
    // ===== role g1: 32 gate rows (8 hidden x 4 gates), K=2048 2-way split ==
    const int g1i = bid - NG0;
    const int rt = wid & 1, par = wid >> 1;      // rt: N-row tile, par: K residue
    const int rrow = rt * 16 + lr;
    const f16* wb = p.w1 + (long)((rrow >> 3) * 1024 + g1i * 8 + (rrow & 7)) * 2048 + lq * 8;
    f16x8 wr[32];
#pragma unroll
    for (int r = 0; r < 32; ++r) {
      const int c = (r < 16) ? ((r >> 3) * 16 + (r & 7) * 2 + par)
                             : (32 + ((r - 16) >> 3) * 16 + ((r - 16) & 7) * 2 + par);
      wr[r] = *(const f16x8*)(wb + c * 32);
    }
#pragma unroll
    for (int r = 0; r < 32; ++r) asm volatile("" : "+v"(wr[r]));  // pin in regs
    const f16* a00 = xs[0] + lr * 520 + lq * 8;
    const f16* a01 = a00 + 16 * 520;
    const f16* a10 = xs[1] + lr * 520 + lq * 8;
    const f16* a11 = a10 + 16 * 520;
    const float* bs = p.bs1;
    const int h0 = g1i * 8;

    for (int s = 0; s < NL; ++s) {
      f32x4 acc0 = (f32x4){0.f, 0.f, 0.f, 0.f};
      f32x4 acc1 = (f32x4){0.f, 0.f, 0.f, 0.f};
      // ---- z1prev part (zero at s=0, skip) ----
      if (s > 0) {
        waitflag(p.bar, F_SZ1 + (g1i & 7), (unsigned)s);
        stage(xs[0], p.zout + (long)(s - 1) * (NB * ND), ND, true);
        stage(xs[1], p.zout + (long)(s - 1) * (NB * ND) + 512, ND, true);
        __syncthreads();
#pragma unroll
        for (int j = 0; j < 8; ++j) {
          const int co = (2 * j + par) * 32;
          acc0 = __builtin_amdgcn_mfma_f32_16x16x32_f16(*(const f16x8*)(a00 + co), wr[16 + j], acc0, 0, 0, 0);
          acc1 = __builtin_amdgcn_mfma_f32_16x16x32_f16(*(const f16x8*)(a01 + co), wr[16 + j], acc1, 0, 0, 0);
        }
#pragma unroll
        for (int j = 0; j < 8; ++j) {
          const int co = (2 * j + par) * 32;
          acc0 = __builtin_amdgcn_mfma_f32_16x16x32_f16(*(const f16x8*)(a10 + co), wr[24 + j], acc0, 0, 0, 0);
          acc1 = __builtin_amdgcn_mfma_f32_16x16x32_f16(*(const f16x8*)(a11 + co), wr[24 + j], acc1, 0, 0, 0);
        }
        __syncthreads();
      }
      // ---- z0 part + finalize z1/c1 ----
      waitflag(p.bar, F_SZ0 + (bid & 15), (unsigned)(s + 1));
      stage(xs[0], p.z0seq + (long)s * (NB * ND), ND, true);
      stage(xs[1], p.z0seq + (long)s * (NB * ND) + 512, ND, true);
      __syncthreads();
#pragma unroll
      for (int j = 0; j < 8; ++j) {
        const int co = (2 * j + par) * 32;
        acc0 = __builtin_amdgcn_mfma_f32_16x16x32_f16(*(const f16x8*)(a00 + co), wr[j], acc0, 0, 0, 0);
        acc1 = __builtin_amdgcn_mfma_f32_16x16x32_f16(*(const f16x8*)(a01 + co), wr[j], acc1, 0, 0, 0);
      }
#pragma unroll
      for (int j = 0; j < 8; ++j) {
        const int co = (2 * j + par) * 32;
        acc0 = __builtin_amdgcn_mfma_f32_16x16x32_f16(*(const f16x8*)(a10 + co), wr[8 + j], acc0, 0, 0, 0);
        acc1 = __builtin_amdgcn_mfma_f32_16x16x32_f16(*(const f16x8*)(a11 + co), wr[8 + j], acc1, 0, 0, 0);
      }
#pragma unroll
      for (int reg = 0; reg < 4; ++reg) {
        gacc[par * 1056 + (lq * 4 + reg) * 33 + rrow]      = acc0[reg];
        gacc[par * 1056 + (16 + lq * 4 + reg) * 33 + rrow] = acc1[reg];
      }
      __syncthreads();
      if (tid < 128) {
        const int b = tid & 31, hp = tid >> 5;
        float z[2];
#pragma unroll
        for (int u = 0; u < 2; ++u) {
          const int hh = hp * 2 + u;
          float gi = gacc[b * 33 + hh]      + gacc[1056 + b * 33 + hh]      + bs[h0 + hh];
          float gf = gacc[b * 33 + 8 + hh]  + gacc[1056 + b * 33 + 8 + hh]  + bs[1024 + h0 + hh];
          float gv = gacc[b * 33 + 16 + hh] + gacc[1056 + b * 33 + 16 + hh] + bs[2048 + h0 + hh];
          float go = gacc[b * 33 + 24 + hh] + gacc[1056 + b * 33 + 24 + hh] + bs[3072 + h0 + hh];
          float cn = sigf(gf) * cbuf[b * 8 + hh] + sigf(gi) * tanhf_fast(gv);
          cbuf[b * 8 + hh] = cn;
          z[u] = sigf(go) * tanhf_fast(cn);
        }
        astore32((unsigned*)p.zout + ((long)s * (NB * ND) + b * ND + h0) / 2 + hp,
                 pack2(z[0], z[1]));
      }
      __syncthreads();
      if (tid == 0)
        sigstep(p.bar, S_SZ1 + (g1i & 7), 16u * (s + 1), R_SZ1, 8u * (s + 1),
                F_SZ1, 8, (unsigned)(s + 1));
    }
  } else {
    // ========== role attention+dec (one block per batch b) =================
    const int b = bid - (NG0 + NG1);
    const int hlen = p.hlens[b];
    float* epart = (float*)xs;               // [4][512]
    float* apart = (float*)xs + 2048;        // [4][512]
    float* wL    = (float*)xs + 4096;        // [512]
    f16*   zbuf  = (f16*)((float*)xs + 4608); // [1024] f16 (z0[b])
    float* dred  = (float*)xs + 5120;        // [256] k-split partials
    float* decF  = gacc;                     // [320]
    float* red   = cbuf;                     // [4]
    const f16* pe  = p.preT + (long)b * NA * 512;   // [a][t]
    const f16* ph  = p.hs   + (long)b * 512 * 512;  // [t][e]

    for (int s = 0; s < NL; ++s) {
      // ---- fused dec(s) = tanh(z0(s-1)[b] @ Wdec^T) ----
      if (s > 0) {
        waitflag(p.bar, F_SZ0 + (bid & 15), (unsigned)s);
        unsigned long long v = aload64(
            (const unsigned long long*)(p.z0seq + (long)(s - 1) * (NB * ND) + (long)b * ND) + tid);
        *(unsigned long long*)(zbuf + tid * 4) = v;
      } else {
        *(unsigned long long*)(zbuf + tid * 4) = 0ull;
      }
      __syncthreads();
      {
        const f16x8* zb = (const f16x8*)zbuf;
        // round 1: a = tid (0..255)
        const f16x8* wrow = (const f16x8*)(p.wdec + (long)tid * ND);
        float acc = 0.f;
#pragma unroll 8
        for (int k = 0; k < 128; ++k) acc = dot8(wrow[k], zb[k], acc);
        decF[tid] = tanhf_fast(acc);
        // round 2: a = 256 + (tid>>2), k-quarter (tid&3), 4-way split
        const int kq = tid & 3;
        const f16x8* wrow2 = (const f16x8*)(p.wdec + (long)(256 + (tid >> 2)) * ND) + kq * 32;
        const f16x8* zb2 = zb + kq * 32;
        float acc2 = 0.f;
#pragma unroll 8
        for (int k = 0; k < 32; ++k) acc2 = dot8(wrow2[k], zb2[k], acc2);
        dred[tid] = acc2;
      }
      __syncthreads();
      if (tid < 64)
        decF[256 + tid] = tanhf_fast(dred[tid * 4] + dred[tid * 4 + 1] +
                                     dred[tid * 4 + 2] + dred[tid * 4 + 3]);
      __syncthreads();
      // ---- e partials: wave w covers a in [80w,80w+80); lane = t-group ----
      {
        float ea[8] = {0.f,0.f,0.f,0.f,0.f,0.f,0.f,0.f};
#pragma unroll 8
        for (int aa = 0; aa < 80; ++aa) {
          const int a = wid * 80 + aa;
          f16x8 pv = *(const f16x8*)(pe + (long)a * 512 + lane * 8);
          const float d = decF[a];
#pragma unroll
          for (int j = 0; j < 8; ++j) ea[j] += (float)pv[j] * d;
        }
#pragma unroll
        for (int j = 0; j < 8; ++j) epart[wid * 512 + lane * 8 + j] = ea[j];
      }
      __syncthreads();
      const int t0 = 2 * tid, t1 = 2 * tid + 1;
      float e0 = (epart[t0] + epart[512 + t0] + epart[1024 + t0] + epart[1536 + t0]) * 2.0f;
      float e1 = (epart[t1] + epart[512 + t1] + epart[1024 + t1] + epart[1536 + t1]) * 2.0f;
      float m = fmaxf((t0 < hlen) ? e0 : -3e38f, (t1 < hlen) ? e1 : -3e38f);
#pragma unroll
      for (int off = 1; off < 64; off <<= 1) m = fmaxf(m, __shfl_xor(m, off));
      if (lane == 0) red[wid] = m;
      __syncthreads();
      const float M = fmaxf(fmaxf(red[0], red[1]), fmaxf(red[2], red[3]));
      float w0 = (t0 < hlen) ? __expf(e0 - M) : 0.f;
      float w1 = (t1 < hlen) ? __expf(e1 - M) : 0.f;
      wL[t0] = w0; wL[t1] = w1;
      float sm = w0 + w1;
#pragma unroll
      for (int off = 1; off < 64; off <<= 1) sm += __shfl_xor(sm, off);
      __syncthreads();               // wL visible + red reusable
      if (lane == 0) red[wid] = sm;
      __syncthreads();
      const float inv = 1.0f / (red[0] + red[1] + red[2] + red[3]);
      // ---- att_c partials: wave w covers t chunk, bounded by hlen ----
      {
        float ac[8] = {0.f,0.f,0.f,0.f,0.f,0.f,0.f,0.f};
        const int tbase = wid * 128;
        const int tcnt = (hlen > tbase) ? ((hlen - tbase < 128) ? (hlen - tbase) : 128) : 0;
#pragma unroll 8
        for (int tt = 0; tt < tcnt; ++tt) {
          const int t = tbase + tt;
          f16x8 hv = *(const f16x8*)(ph + (long)t * 512 + lane * 8);
          const float w = wL[t];
#pragma unroll
          for (int j = 0; j < 8; ++j) ac[j] += (float)hv[j] * w;
        }
#pragma unroll
        for (int j = 0; j < 8; ++j) apart[wid * 512 + lane * 8 + j] = ac[j];
      }
      __syncthreads();
      {
        float s0 = apart[t0] + apart[512 + t0] + apart[1024 + t0] + apart[1536 + t0];
        float s1 = apart[t1] + apart[512 + t1] + apart[1024 + t1] + apart[1536 + t1];
        astore32((unsigned*)p.att + b * 256 + tid, pack2(s0 * inv, s1 * inv));
      }
      __syncthreads();
      if (tid == 0)
        sigstep(p.bar, S_SATT + (b & 3), 8u * (s + 1), R_SATT, 4u * (s + 1),
                F_SATT, 16, (unsigned)(s + 1));
    }
  }
}

// ------------------------- logits GEMM + fused CE stats --------------------
__global__ void __launch_bounds__(256) k_lgemm(const f16* __restrict__ z, const f16* __restrict__ wout,
                                               const float* __restrict__ bout, float4* __restrict__ part) {
  const int mb = blockIdx.x, nb = blockIdx.y;
  const int wid = threadIdx.x >> 6, lane = threadIdx.x & 63;
  const int lr = lane & 15, lq = lane >> 4;
  const int m0 = mb * 32;
  const int n0 = nb * 512 + wid * 128;
  const f16* arow0 = z + (long)(m0 + lr) * 1024 + lq * 8;
  const f16* arow1 = arow0 + (long)16 * 1024;
  const f16* bp[8];
  int cols[8];
#pragma unroll
  for (int nt = 0; nt < 8; ++nt) {
    int n = n0 + nt * 16 + lr;
    cols[nt] = n;
    int nc = (n < NO) ? n : (NO - 1);
    bp[nt] = wout + (long)nc * 1024 + lq * 8;
  }
  f32x4 acc[16];
#pragma unroll
  for (int i = 0; i < 16; ++i) acc[i] = (f32x4){0.f, 0.f, 0.f, 0.f};
  for (int kk = 0; kk < 1024; kk += 32) {
    f16x8 a0v = *(const f16x8*)(arow0 + kk);
    f16x8 a1v = *(const f16x8*)(arow1 + kk);
#pragma unroll
    for (int nt = 0; nt < 8; ++nt) {
      f16x8 bv = *(const f16x8*)(bp[nt] + kk);
      acc[nt]     = __builtin_amdgcn_mfma_f32_16x16x32_f16(a0v, bv, acc[nt], 0, 0, 0);
      acc[8 + nt] = __builtin_amdgcn_mfma_f32_16x16x32_f16(a1v, bv, acc[8 + nt], 0, 0, 0);
    }
  }
  float bias[8];
#pragma unroll
  for (int nt = 0; nt < 8; ++nt) bias[nt] = (cols[nt] < NO) ? bout[cols[nt]] : 0.f;
  const int chunk = nb * 4 + wid;
#pragma unroll
  for (int mt = 0; mt < 2; ++mt) {
#pragma unroll
    for (int reg = 0; reg < 4; ++reg) {
      float vals[8];
      float mx = -1e30f, av = -1e30f; int ai = 0;
#pragma unroll
      for (int nt = 0; nt < 8; ++nt) {
        float v = (cols[nt] < NO) ? (acc[mt * 8 + nt][reg] + bias[nt]) : -1e30f;
        vals[nt] = v;
        mx = fmaxf(mx, v);
        if (v > av) { av = v; ai = cols[nt]; }
      }
      float sum = 0.f;
#pragma unroll
      for (int nt = 0; nt < 8; ++nt) sum += (vals[nt] > -9e29f) ? __expf(vals[nt] - mx) : 0.f;
#pragma unroll
      for (int off = 1; off < 16; off <<= 1) {
        float mo = __shfl_xor(mx, off);
        float so = __shfl_xor(sum, off);
        float avo = __shfl_xor(av, off);
        int aio = __shfl_xor(ai, off);
        float nm = fmaxf(mx, mo);
        float e1 = (mx > -9e29f) ? __expf(mx - nm) : 0.f;
        float e2 = (mo > -9e29f) ? __expf(mo - nm) : 0.f;
        sum = sum * e1 + so * e2;
        mx = nm;
        if (avo > av || (avo == av && aio < ai)) { av = avo; ai = aio; }
      }
      if (lr == 0) {
        int rowg = m0 + mt * 16 + lq * 4 + reg;
        float4 q; q.x = mx; q.y = sum; q.z = av; q.w = __int_as_float(ai);
        part[(long)rowg * 80 + chunk] = q;
      }
    }
  }
}

__global__ void k_tl(const f16* __restrict__ z, const f16* __restrict__ wout,
                     const float* __restrict__ bout, const int* __restrict__ ys, float* __restrict__ tl) {
  const int tok = blockIdx.x * 4 + (threadIdx.x >> 6);
  const int lane = threadIdx.x & 63;
  if (tok >= NTOK) return;
  const int s = tok >> 5, b = tok & 31;
  const int tgt = (s < 128) ? ys[b * 128 + s] : SOS_ID;
  const f16x8* zp = (const f16x8*)(z + (long)tok * 1024);
  const f16x8* wp = (const f16x8*)(wout + (long)tgt * 1024);
  float acc = 0.f;
  acc = dot8(zp[lane], wp[lane], acc);
  acc = dot8(zp[64 + lane], wp[64 + lane], acc);
#pragma unroll
  for (int off = 32; off > 0; off >>= 1) acc += __shfl_xor(acc, off);
  if (lane == 0) tl[tok] = acc + bout[tgt];
}

__global__ void k_ce(const float4* __restrict__ part, const float* __restrict__ tl,
                     const int* __restrict__ ys, float* scal) {
  const int m = blockIdx.x * 256 + threadIdx.x;
  float nll = 0.f, okf = 0.f;
  if (m < NTOK) {
    float M = -1e30f, S = 0.f, av = -1e30f; int ai = 0;
    for (int c = 0; c < 80; ++c) {
      float4 q = part[(long)m * 80 + c];
      float qm = q.x, qs = q.y, qa = q.z; int qi = __float_as_int(q.w);
      float nm = fmaxf(M, qm);
      float e1 = (M > -9e29f) ? __expf(M - nm) : 0.f;
      float e2 = (qm > -9e29f) ? __expf(qm - nm) : 0.f;
      S = S * e1 + qs * e2; M = nm;
      if (qa > av || (qa == av && qi < ai)) { av = qa; ai = qi; }
    }
    float lse = M + __logf(S);
    int s = m >> 5, b = m & 31;
    int tgt = (s < 128) ? ys[b * 128 + s] : SOS_ID;
    nll = lse - tl[m];
    okf = (ai == tgt) ? 1.f : 0.f;
  }
  __shared__ float r1[256], r2[256];
  r1[threadIdx.x] = nll; r2[threadIdx.x] = okf; __syncthreads();
  for (int st = 128; st > 0; st >>= 1) {
    if (threadIdx.x < st) { r1[threadIdx.x] += r1[threadIdx.x + st]; r2[threadIdx.x] += r2[threadIdx.x + st]; }
    __syncthreads();
  }
  if (threadIdx.x == 0) { atomicAdd(&scal[0], r1[0]); atomicAdd(&scal[1], r2[0]); }
}

__global__ void k_final(const float* scal, float* out) {
  if (threadIdx.x == 0) {
    float loss = scal[0] * (128.f / 4128.f);
    out[0] = loss;
    out[1] = scal[1] * (1.f / 4128.f);
    out[2] = expf(loss / 32.f);
  }
}

// --------------------------------- launch ----------------------------------
extern "C" void kernel_launch(void* const* d_in, const int* in_sizes, int n_in,
                              void* d_out, int out_size, void* d_ws, size_t ws_size,
                              hipStream_t stream) {
  const float* hs_pad = (const float*)d_in[0];
  const int* hlens    = (const int*)d_in[1];
  const int* ys_pad   = (const int*)d_in[2];
  const float* embed  = (const float*)d_in[3];
  const float* Wenc   = (const float*)d_in[4];
  const float* benc   = (const float*)d_in[5];
  const float* Wdec   = (const float*)d_in[6];
  const float* Wih0   = (const float*)d_in[7];
  const float* Whh0   = (const float*)d_in[8];
  const float* bih0   = (const float*)d_in[9];
  const float* bhh0   = (const float*)d_in[10];
  const float* Wih1   = (const float*)d_in[11];
  const float* Whh1   = (const float*)d_in[12];
  const float* bih1   = (const float*)d_in[13];
  const float* bhh1   = (const float*)d_in[14];
  const float* Wout   = (const float*)d_in[15];
  const float* bout   = (const float*)d_in[16];
  float* out = (float*)d_out;
  (void)in_sizes; (void)n_in; (void)out_size; (void)ws_size;

  char* ws = (char*)d_ws;
  size_t off = 0;
  auto alloc = [&](size_t bytes) -> char* {
    char* pp = ws + off;
    off = (off + bytes + 255) & ~(size_t)255;
    return pp;
  };
  f16* hs16    = (f16*)alloc((size_t)NB * NTT * NE * 2);
  f16* preT    = (f16*)alloc((size_t)NB * NA * NTT * 2);
  f16* eys16   = (f16*)alloc((size_t)NL * NB * ND * 2);
  f16* w0cat   = (f16*)alloc((size_t)4096 * 2560 * 2);
  f16* w1cat   = (f16*)alloc((size_t)4096 * 2048 * 2);
  f16* wdec16  = (f16*)alloc((size_t)NA * ND * 2);
  f16* wenc16  = (f16*)alloc((size_t)NA * NE * 2);
  f16* wout16  = (f16*)alloc((size_t)NO * ND * 2);
  f16* zout    = (f16*)alloc((size_t)NTOK * ND * 2);
  f16* z0seq   = (f16*)alloc((size_t)NL * NB * ND * 2);
  f16* att16   = (f16*)alloc((size_t)NB * NE * 2);
  float* bs0   = (float*)alloc(4096 * 4);
  float* bs1   = (float*)alloc(4096 * 4);
  float* tl    = (float*)alloc((size_t)NTOK * 4);
  float4* part = (float4*)alloc((size_t)NTOK * 80 * 16);
  float* scal  = (float*)alloc(256);
  unsigned* bar = (unsigned*)alloc(16384);

  k_cvt<<<dim3(2048), dim3(256), 0, stream>>>(hs_pad, hs16, (long)NB * NTT * NE);
  k_cvt<<<dim3(256), dim3(256), 0, stream>>>(Wdec, wdec16, (long)NA * ND);
  k_cvt<<<dim3(128), dim3(256), 0, stream>>>(Wenc, wenc16, (long)NA * NE);
  k_cvt<<<dim3(2048), dim3(256), 0, stream>>>(Wout, wout16, (long)NO * ND);
  k_w0cat<<<dim3(10, 4096), dim3(256), 0, stream>>>(Wih0, Whh0, w0cat);
  k_w1cat<<<dim3(8, 4096), dim3(256), 0, stream>>>(Wih1, Whh1, w1cat);
  k_eys<<<dim3(4, NL * NB), dim3(256), 0, stream>>>(ys_pad, embed, eys16);
  k_pre<<<dim3(512), dim3(256), 0, stream>>>(hs16, wenc16, benc, preT);
  k_bias<<<dim3(16), dim3(256), 0, stream>>>(bih0, bhh0, bih1, bhh1, bs0, bs1);
  k_zero<<<dim3(128), dim3(256), 0, stream>>>(scal, bar);

  LoopP lp;
  lp.preT = preT; lp.hs = hs16; lp.eys = eys16; lp.w0 = w0cat; lp.w1 = w1cat; lp.wdec = wdec16;
  lp.bs0 = bs0; lp.bs1 = bs1; lp.hlens = hlens;
  lp.att = att16; lp.z0seq = z0seq; lp.zout = zout; lp.bar = bar;
  k_loop<<<dim3(GRID_LOOP), dim3(256), 0, stream>>>(lp);

  k_tl<<<dim3(NTOK / 4), dim3(256), 0, stream>>>(zout, wout16, bout, ys_pad, tl);
  k_lgemm<<<dim3(129, 20), dim3(256), 0, stream>>>(zout, wout16, bout, part);
  k_ce<<<dim3(17), dim3(256), 0, stream>>>(part, tl, ys_pad, scal);
  k_final<<<dim3(1), dim3(64), 0, stream>>>(scal, out);
}

// Round 5
// 6647.169 us; speedup vs baseline: 1.9621x; 1.0039x over previous
//
#include <hip/hip_runtime.h>
#include <hip/hip_fp16.h>
#include <math.h>

// ---------------------------------------------------------------------------
// Decoder (ESPnet AttDot + 2x LSTMCell + CE) on gfx950.
// R8 -> R9: cached staging loads (the broadcast rides the L2).
//  R8 recount: each stage() is 32KB; the grid staged ~41 MB/step of sc1
//  L2-BYPASSING atomic loads (g0 96KB x256 + g1 128KB x128) -- every block
//  paying L3/HBM latency for the same 160KB of per-step payload. That
//  service time IS the 40us step. All recurrent buffers are write-once
//  sequenced (z0seq[s], zout[s], new attseq[s]): fresh 128B-aligned
//  addresses each step, never in any L1/L2 (producers store sc1, straight
//  to L3) => NORMAL cached loads are safe. First reader per XCD fills L2
//  from L3 (~160KB/step), remaining ~47 blocks hit L2. Data stores stay
//  sc1; flag protocol (vmcnt drain -> relaxed fetch_add tree) unchanged.
// ---------------------------------------------------------------------------

typedef _Float16 f16;
typedef _Float16 f16x2 __attribute__((ext_vector_type(2)));
typedef _Float16 f16x4 __attribute__((ext_vector_type(4)));
typedef _Float16 f16x8 __attribute__((ext_vector_type(8)));
typedef float f32x4 __attribute__((ext_vector_type(4)));

#define SOS_ID 9999
#define NB 32
#define NTT 512
#define NE 512
#define ND 1024
#define NA 320
#define NO 10000
#define NL 129
#define NTOK (NL*NB)
#define NG0 256
#define NG1 128
#define GRID_LOOP 416   // 256 g0 + 128 g1 + 32 att

// signal slot indices (unsigned slots, stride 32 = one 128B line each)
#define S_SZ0  0
#define R_SZ0  16
#define S_SZ1  17
#define R_SZ1  25
#define S_SATT 26
#define R_SATT 30
#define F_SZ0  64
#define F_SZ1  80
#define F_SATT 88

union PU32 { unsigned u; f16x2 h; };
union PU64 { unsigned long long u; f16x4 h; unsigned w[2]; };

__device__ __forceinline__ float fdot2f(f16x2 a, f16x2 b, float c) {
#if __has_builtin(__builtin_amdgcn_fdot2)
  return __builtin_amdgcn_fdot2(a, b, c, false);
#else
  return c + (float)a[0]*(float)b[0] + (float)a[1]*(float)b[1];
#endif
}
__device__ __forceinline__ float dot8(f16x8 a, f16x8 b, float acc) {
  acc = fdot2f(__builtin_shufflevector(a, a, 0, 1), __builtin_shufflevector(b, b, 0, 1), acc);
  acc = fdot2f(__builtin_shufflevector(a, a, 2, 3), __builtin_shufflevector(b, b, 2, 3), acc);
  acc = fdot2f(__builtin_shufflevector(a, a, 4, 5), __builtin_shufflevector(b, b, 4, 5), acc);
  acc = fdot2f(__builtin_shufflevector(a, a, 6, 7), __builtin_shufflevector(b, b, 6, 7), acc);
  return acc;
}
__device__ __forceinline__ float sigf(float x) { return 1.0f / (1.0f + __expf(-x)); }
__device__ __forceinline__ float tanhf_fast(float x) { return 1.0f - 2.0f / (1.0f + __expf(2.0f * x)); }

__device__ __forceinline__ void astore32(void* p, unsigned v) {
  __hip_atomic_store((unsigned*)p, v, __ATOMIC_RELAXED, __HIP_MEMORY_SCOPE_AGENT);
}
__device__ __forceinline__ unsigned pack2(float a, float b) {
  PU32 u; u.h[0] = (f16)a; u.h[1] = (f16)b; return u.u;
}

// producer-side signal: sub counter -> root counter -> replicated flags.
// All RELAXED: callers invoke from tid 0 after __syncthreads(), which drains
// each wave's vmcnt => all block stores (sc1, L2-bypass) are at L3 already.
__device__ __forceinline__ void sigstep(unsigned* bar, int sub, unsigned subtgt,
                                        int root, unsigned roottgt,
                                        int flag0, int nrep, unsigned val) {
  asm volatile("s_waitcnt vmcnt(0)" ::: "memory");
  unsigned old = __hip_atomic_fetch_add(&bar[sub * 32], 1u, __ATOMIC_RELAXED, __HIP_MEMORY_SCOPE_AGENT);
  if (old + 1u == subtgt) {
    unsigned r = __hip_atomic_fetch_add(&bar[root * 32], 1u, __ATOMIC_RELAXED, __HIP_MEMORY_SCOPE_AGENT);
    if (r + 1u == roottgt) {
      for (int i = 0; i < nrep; ++i)
        __hip_atomic_store(&bar[(flag0 + i) * 32], val, __ATOMIC_RELAXED, __HIP_MEMORY_SCOPE_AGENT);
    }
  }
}
// consumer-side wait on a replicated flag
__device__ __forceinline__ void waitflag(unsigned* bar, int slot, unsigned val) {
  if (threadIdx.x == 0) {
    while (__hip_atomic_load(&bar[slot * 32], __ATOMIC_RELAXED, __HIP_MEMORY_SCOPE_AGENT) < val)
      __builtin_amdgcn_s_sleep(1);
  }
  __syncthreads();
  asm volatile("" ::: "memory");
}

// ------------------------------ prep kernels -------------------------------
__global__ void k_cvt(const float* __restrict__ s, f16* __restrict__ d, long n) {
  long i = (long)blockIdx.x * 256 + threadIdx.x;
  long st = (long)gridDim.x * 256;
  for (; i < n; i += st) d[i] = (f16)s[i];
}
// w0cat cols: [0:1024)=Wih0 ey part, [1024:2048)=Whh0 (z0prev), [2048:2560)=Wih0 att part
__global__ void k_w0cat(const float* __restrict__ wih, const float* __restrict__ whh, f16* __restrict__ dst) {
  int j = blockIdx.y; int k = blockIdx.x * 256 + threadIdx.x;
  float v;
  if (k < 1024)      v = wih[(long)j * 1536 + k];
  else if (k < 2048) v = whh[(long)j * 1024 + (k - 1024)];
  else               v = wih[(long)j * 1536 + 1024 + (k - 2048)];
  dst[(long)j * 2560 + k] = (f16)v;
}
// w1cat cols: [0:1024)=Wih1 (z0), [1024:2048)=Whh1 (z1prev)
__global__ void k_w1cat(const float* __restrict__ wih, const float* __restrict__ whh, f16* __restrict__ dst) {
  int j = blockIdx.y; int k = blockIdx.x * 256 + threadIdx.x;
  float v = (k < 1024) ? wih[(long)j * 1024 + k] : whh[(long)j * 1024 + (k - 1024)];
  dst[(long)j * 2048 + k] = (f16)v;
}
__global__ void k_eys(const int* __restrict__ ys, const float* __restrict__ emb, f16* __restrict__ eys) {
  int sb = blockIdx.y; int k = blockIdx.x * 256 + threadIdx.x;
  int s = sb >> 5, b = sb & 31;
  int tok = (s == 0) ? SOS_ID : ys[b * 128 + (s - 1)];
  eys[(long)sb * 1024 + k] = (f16)emb[(long)tok * 1024 + k];
}
// preT[b][a][t] = tanh(hs[b][t][:].wenc[a][:] + benc[a])  (t-contiguous)
__global__ void k_pre(const f16* __restrict__ hs, const f16* __restrict__ wenc,
                      const float* __restrict__ benc, f16* __restrict__ preT) {
  const int row0 = blockIdx.x * 32;
  for (int idx = threadIdx.x; idx < 32 * NA; idx += 256) {
    int r = row0 + idx / NA, a = idx % NA;
    const f16x8* hp = (const f16x8*)(hs + (long)r * NE);
    const f16x8* wp = (const f16x8*)(wenc + (long)a * NE);
    float acc = 0.f;
#pragma unroll 4
    for (int k = 0; k < 64; ++k) acc = dot8(hp[k], wp[k], acc);
    int b = r >> 9, t = r & 511;
    preT[((long)b * NA + a) * 512 + t] = (f16)tanhf_fast(acc + benc[a]);
  }
}
__global__ void k_bias(const float* a0, const float* b0, const float* a1, const float* b1,
                       float* s0, float* s1) {
  int i = blockIdx.x * 256 + threadIdx.x;
  if (i < 4096) { s0[i] = a0[i] + b0[i]; s1[i] = a1[i] + b1[i]; }
}
__global__ void k_zero(float* scal, unsigned* bar) {
  int i = blockIdx.x * 256 + threadIdx.x;
  if (i < 4096) bar[i] = 0u;
  if (i < 8) scal[i] = 0.f;
}

// ------------------------------ persistent loop ----------------------------
struct LoopP {
  const f16 *preT, *hs, *eys, *w0, *w1, *wdec;
  const float *bs0, *bs1;
  const int* hlens;
  f16 *att, *z0seq, *zout;   // att = attseq[NL][32][512]
  unsigned* bar;
};

__global__ void __launch_bounds__(256, 2) k_loop(LoopP p) {
  __shared__ __align__(16) f16 xs[2][32 * 520];  // 2 staging tiles, 66560 B
  __shared__ float gacc[2176];                   // gate partials / decF
  __shared__ float cbuf[256];                    // c-state slice / att reduce

  const int bid = blockIdx.x, tid = threadIdx.x;
  const int wid = tid >> 6, lane = tid & 63, lr = lane & 15, lq = lane >> 4;
  cbuf[tid] = 0.f;
  __syncthreads();

  // stage one 32x512 f16 tile into dst (row stride 520), cached loads
  auto stage = [&](f16* dst, const f16* src, long rs) {
    for (int idx = tid; idx < 4096; idx += 256) {
      int r = idx >> 7, c = idx & 127;
      *(unsigned long long*)(dst + r * 520 + c * 4) =
          *(const unsigned long long*)(src + (long)r * rs + c * 4);
    }
  };

  if (bid < NG0) {
    // ===== role g0: 16 gate rows (4 hidden x 4 gates), K=2560 4-way split ==
    const int par = wid;                         // K-chunk residue mod 4
    const f16* wb = p.w0 + (long)((lr >> 2) * 1024 + bid * 4 + (lr & 3)) * 2560 + lq * 8;
    f16x8 wr[20];
#pragma unroll
    for (int r = 0; r < 20; ++r) {
      const int c = (r < 16) ? ((r >> 2) * 16 + (r & 3) * 4 + par)
                             : (64 + (r - 16) * 4 + par);
      wr[r] = *(const f16x8*)(wb + c * 32);
    }
#pragma unroll
    for (int r = 0; r < 20; ++r) asm volatile("" : "+v"(wr[r]));  // pin in regs
    const f16* a00 = xs[0] + lr * 520 + lq * 8;
    const f16* a01 = a00 + 16 * 520;
    const f16* a10 = xs[1] + lr * 520 + lq * 8;
    const f16* a11 = a10 + 16 * 520;
    const float* bs = p.bs0;

    // prologue: eys(0) into both tiles
    stage(xs[0], p.eys, ND);
    stage(xs[1], p.eys + 512, ND);
    __syncthreads();

    for (int s = 0; s < NL; ++s) {
      f32x4 acc0 = (f32x4){0.f, 0.f, 0.f, 0.f};
      f32x4 acc1 = (f32x4){0.f, 0.f, 0.f, 0.f};
      // ---- Phase A1: ey (prefetched) ----
#pragma unroll
      for (int j = 0; j < 4; ++j) {
        const int co = (4 * j + par) * 32;
        acc0 = __builtin_amdgcn_mfma_f32_16x16x32_f16(*(const f16x8*)(a00 + co), wr[j], acc0, 0, 0, 0);
        acc1 = __builtin_amdgcn_mfma_f32_16x16x32_f16(*(const f16x8*)(a01 + co), wr[j], acc1, 0, 0, 0);
      }
#pragma unroll
      for (int j = 0; j < 4; ++j) {
        const int co = (4 * j + par) * 32;
        acc0 = __builtin_amdgcn_mfma_f32_16x16x32_f16(*(const f16x8*)(a10 + co), wr[4 + j], acc0, 0, 0, 0);
        acc1 = __builtin_amdgcn_mfma_f32_16x16x32_f16(*(const f16x8*)(a11 + co), wr[4 + j], acc1, 0, 0, 0);
      }
      __syncthreads();
      // ---- Phase A2: z0prev (zero at s=0, skip) ----
      if (s > 0) {
        waitflag(p.bar, F_SZ0 + (bid & 15), (unsigned)s);
        stage(xs[0], p.z0seq + (long)(s - 1) * (NB * ND), ND);
        stage(xs[1], p.z0seq + (long)(s - 1) * (NB * ND) + 512, ND);
        __syncthreads();
#pragma unroll
        for (int j = 0; j < 4; ++j) {
          const int co = (4 * j + par) * 32;
          acc0 = __builtin_amdgcn_mfma_f32_16x16x32_f16(*(const f16x8*)(a00 + co), wr[8 + j], acc0, 0, 0, 0);
          acc1 = __builtin_amdgcn_mfma_f32_16x16x32_f16(*(const f16x8*)(a01 + co), wr[8 + j], acc1, 0, 0, 0);
        }
#pragma unroll
        for (int j = 0; j < 4; ++j) {
          const int co = (4 * j + par) * 32;
          acc0 = __builtin_amdgcn_mfma_f32_16x16x32_f16(*(const f16x8*)(a10 + co), wr[12 + j], acc0, 0, 0, 0);
          acc1 = __builtin_amdgcn_mfma_f32_16x16x32_f16(*(const f16x8*)(a11 + co), wr[12 + j], acc1, 0, 0, 0);
        }
        __syncthreads();
      }
      // ---- Phase B: att part (K 2048:2560) + finalize z0/c0 ----
      waitflag(p.bar, F_SATT + (bid & 15), (unsigned)(s + 1));
      stage(xs[0], p.att + (long)s * (NB * NE), NE);
      __syncthreads();
#pragma unroll
      for (int j = 0; j < 4; ++j) {
        const int co = (4 * j + par) * 32;
        acc0 = __builtin_amdgcn_mfma_f32_16x16x32_f16(*(const f16x8*)(a00 + co), wr[16 + j], acc0, 0, 0, 0);
        acc1 = __builtin_amdgcn_mfma_f32_16x16x32_f16(*(const f16x8*)(a01 + co), wr[16 + j], acc1, 0, 0, 0);
      }
#pragma unroll
      for (int reg = 0; reg < 4; ++reg) {
        gacc[par * 544 + (lq * 4 + reg) * 17 + lr]      = acc0[reg];
        gacc[par * 544 + (16 + lq * 4 + reg) * 17 + lr] = acc1[reg];
      }
      __syncthreads();
      if (tid < 64) {
        const int b = tid & 31, q = tid >> 5;   // q=0 -> hh 0,1 ; q=1 -> hh 2,3
        float z[2];
#pragma unroll
        for (int u = 0; u < 2; ++u) {
          const int hh = q * 2 + u;
          float gi = 0.f, gf = 0.f, gv = 0.f, go = 0.f;
#pragma unroll
          for (int pp = 0; pp < 4; ++pp) {
            const float* gp = gacc + pp * 544 + b * 17;
            gi += gp[hh]; gf += gp[4 + hh]; gv += gp[8 + hh]; go += gp[12 + hh];
          }
          const int hb = bid * 4 + hh;
          gi += bs[hb]; gf += bs[1024 + hb]; gv += bs[2048 + hb]; go += bs[3072 + hb];
          float cn = sigf(gf) * cbuf[b * 4 + hh] + sigf(gi) * tanhf_fast(gv);
          cbuf[b * 4 + hh] = cn;
          z[u] = sigf(go) * tanhf_fast(cn);
        }
        astore32((unsigned*)p.z0seq + ((long)s * (NB * ND) + b * ND + bid * 4) / 2 + q,
                 pack2(z[0], z[1]));
      }
      __syncthreads();
      if (tid == 0)
        sigstep(p.bar, S_SZ0 + (bid & 15), 16u * (s + 1), R_SZ0, 16u * (s + 1),
                F_SZ0, 16, (unsigned)(s + 1));
      // ---- Phase C: prefetch eys(s+1) ----
      if (s + 1 < NL) {
        stage(xs[0], p.eys + (long)(s + 1) * (NB * ND), ND);
        stage(xs[1], p.eys + (long)(s + 1) * (NB * ND) + 512, ND);
      }
      __syncthreads();
    }
  } else if (bid < NG0 + NG1) {
    // ===== role g1: 32 gate rows (8 hidden x 4 gates), K=2048 2-way split ==
    const int g1i = bid - NG0;
    const int rt = wid & 1, par = wid >> 1;      // rt: N-row tile, par: K residue
    const int rrow = rt * 16 + lr;
    const f16* wb = p.w1 + (long)((rrow >> 3) * 1024 + g1i * 8 + (rrow & 7)) * 2048 + lq * 8;
    f16x8 wr[32];
#pragma unroll
    for (int r = 0; r < 32; ++r) {
      const int c = (r < 16) ? ((r >> 3) * 16 + (r & 7) * 2 + par)
                             : (32 + ((r - 16) >> 3) * 16 + ((r - 16) & 7) * 2 + par);
      wr[r] = *(const f16x8*)(wb + c * 32);
    }
#pragma unroll
    for (int r = 0; r < 32; ++r) asm volatile("" : "+v"(wr[r]));  // pin in regs
    const f16* a00 = xs[0] + lr * 520 + lq * 8;
    const f16* a01 = a00 + 16 * 520;
    const f16* a10 = xs[1] + lr * 520 + lq * 8;
    const f16* a11 = a10 + 16 * 520;
    const float* bs = p.bs1;
    const int h0 = g1i * 8;

    for (int s = 0; s < NL; ++s) {
      f32x4 acc0 = (f32x4){0.f, 0.f, 0.f, 0.f};
      f32x4 acc1 = (f32x4){0.f, 0.f, 0.f, 0.f};
      // ---- z1prev part (zero at s=0, skip) ----
      if (s > 0) {
        waitflag(p.bar, F_SZ1 + (g1i & 7), (unsigned)s);
        stage(xs[0], p.zout + (long)(s - 1) * (NB * ND), ND);
        stage(xs[1], p.zout + (long)(s - 1) * (NB * ND) + 512, ND);
        __syncthreads();
#pragma unroll
        for (int j = 0; j < 8; ++j) {
          const int co = (2 * j + par) * 32;
          acc0 = __builtin_amdgcn_mfma_f32_16x16x32_f16(*(const f16x8*)(a00 + co), wr[16 + j], acc0, 0, 0, 0);
          acc1 = __builtin_amdgcn_mfma_f32_16x16x32_f16(*(const f16x8*)(a01 + co), wr[16 + j], acc1, 0, 0, 0);
        }
#pragma unroll
        for (int j = 0; j < 8; ++j) {
          const int co = (2 * j + par) * 32;
          acc0 = __builtin_amdgcn_mfma_f32_16x16x32_f16(*(const f16x8*)(a10 + co), wr[24 + j], acc0, 0, 0, 0);
          acc1 = __builtin_amdgcn_mfma_f32_16x16x32_f16(*(const f16x8*)(a11 + co), wr[24 + j], acc1, 0, 0, 0);
        }
        __syncthreads();
      }
      // ---- z0 part + finalize z1/c1 ----
      waitflag(p.bar, F_SZ0 + (bid & 15), (unsigned)(s + 1));
      stage(xs[0], p.z0seq + (long)s * (NB * ND), ND);
      stage(xs[1], p.z0seq + (long)s * (NB * ND) + 512, ND);
      __syncthreads();
#pragma unroll
      for (int j = 0; j < 8; ++j) {
        const int co = (2 * j + par) * 32;
        acc0 = __builtin_amdgcn_mfma_f32_16x16x32_f16(*(const f16x8*)(a00 + co), wr[j], acc0, 0, 0, 0);
        acc1 = __builtin_amdgcn_mfma_f32_16x16x32_f16(*(const f16x8*)(a01 + co), wr[j], acc1, 0, 0, 0);
      }
#pragma unroll
      for (int j = 0; j < 8; ++j) {
        const int co = (2 * j + par) * 32;
        acc0 = __builtin_amdgcn_mfma_f32_16x16x32_f16(*(const f16x8*)(a10 + co), wr[8 + j], acc0, 0, 0, 0);
        acc1 = __builtin_amdgcn_mfma_f32_16x16x32_f16(*(const f16x8*)(a11 + co), wr[8 + j], acc1, 0, 0, 0);
      }
#pragma unroll
      for (int reg = 0; reg < 4; ++reg) {
        gacc[par * 1056 + (lq * 4 + reg) * 33 + rrow]      = acc0[reg];
        gacc[par * 1056 + (16 + lq * 4 + reg) * 33 + rrow] = acc1[reg];
      }
      __syncthreads();
      if (tid < 128) {
        const int b = tid & 31, hp = tid >> 5;
        float z[2];
#pragma unroll
        for (int u = 0; u < 2; ++u) {
          const int hh = hp * 2 + u;
          float gi = gacc[b * 33 + hh]      + gacc[1056 + b * 33 + hh]      + bs[h0 + hh];
          float gf = gacc[b * 33 + 8 + hh]  + gacc[1056 + b * 33 + 8 + hh]  + bs[1024 + h0 + hh];
          float gv = gacc[b * 33 + 16 + hh] + gacc[1056 + b * 33 + 16 + hh] + bs[2048 + h0 + hh];
          float go = gacc[b * 33 + 24 + hh] + gacc[1056 + b * 33 + 24 + hh] + bs[3072 + h0 + hh];
          float cn = sigf(gf) * cbuf[b * 8 + hh] + sigf(gi) * tanhf_fast(gv);
          cbuf[b * 8 + hh] = cn;
          z[u] = sigf(go) * tanhf_fast(cn);
        }
        astore32((unsigned*)p.zout + ((long)s * (NB * ND) + b * ND + h0) / 2 + hp,
                 pack2(z[0], z[1]));
      }
      __syncthreads();
      if (tid == 0)
        sigstep(p.bar, S_SZ1 + (g1i & 7), 16u * (s + 1), R_SZ1, 8u * (s + 1),
                F_SZ1, 8, (unsigned)(s + 1));
    }
  } else {
    // ========== role attention+dec (one block per batch b) =================
    const int b = bid - (NG0 + NG1);
    const int hlen = p.hlens[b];
    float* epart = (float*)xs;               // [4][512]
    float* apart = (float*)xs + 2048;        // [4][512]
    float* wL    = (float*)xs + 4096;        // [512]
    f16*   zbuf  = (f16*)((float*)xs + 4608); // [1024] f16 (z0[b])
    float* dred  = (float*)xs + 5120;        // [256] k-split partials
    float* decF  = gacc;                     // [320]
    float* red   = cbuf;                     // [4]
    const f16* pe  = p.preT + (long)b * NA * 512;   // [a][t]
    const f16* ph  = p.hs   + (long)b * 512 * 512;  // [t][e]

    for (int s = 0; s < NL; ++s) {
      // ---- fused dec(s) = tanh(z0(s-1)[b] @ Wdec^T) ----
      if (s > 0) {
        waitflag(p.bar, F_SZ0 + (bid & 15), (unsigned)s);
        *(unsigned long long*)(zbuf + tid * 4) = *(
            (const unsigned long long*)(p.z0seq + (long)(s - 1) * (NB * ND) + (long)b * ND) + tid);
      } else {
        *(unsigned long long*)(zbuf + tid * 4) = 0ull;
      }
      __syncthreads();
      {
        const f16x8* zb = (const f16x8*)zbuf;
        // round 1: a = tid (0..255)
        const f16x8* wrow = (const f16x8*)(p.wdec + (long)tid * ND);
        float acc = 0.f;
#pragma unroll 8
        for (int k = 0; k < 128; ++k) acc = dot8(wrow[k], zb[k], acc);
        decF[tid] = tanhf_fast(acc);
        // round 2: a = 256 + (tid>>2), k-quarter (tid&3), 4-way split
        const int kq = tid & 3;
        const f16x8* wrow2 = (const f16x8*)(p.wdec + (long)(256 + (tid >> 2)) * ND) + kq * 32;
        const f16x8* zb2 = zb + kq * 32;
        float acc2 = 0.f;
#pragma unroll 8
        for (int k = 0; k < 32; ++k) acc2 = dot8(wrow2[k], zb2[k], acc2);
        dred[tid] = acc2;
      }
      __syncthreads();
      if (tid < 64)
        decF[256 + tid] = tanhf_fast(dred[tid * 4] + dred[tid * 4 + 1] +
                                     dred[tid * 4 + 2] + dred[tid * 4 + 3]);
      __syncthreads();
      // ---- e partials: wave w covers a in [80w,80w+80); lane = t-group ----
      {
        float ea[8] = {0.f,0.f,0.f,0.f,0.f,0.f,0.f,0.f};
#pragma unroll 8
        for (int aa = 0; aa < 80; ++aa) {
          const int a = wid * 80 + aa;
          f16x8 pv = *(const f16x8*)(pe + (long)a * 512 + lane * 8);
          const float d = decF[a];
#pragma unroll
          for (int j = 0; j < 8; ++j) ea[j] += (float)pv[j] * d;
        }
#pragma unroll
        for (int j = 0; j < 8; ++j) epart[wid * 512 + lane * 8 + j] = ea[j];
      }
      __syncthreads();
      const int t0 = 2 * tid, t1 = 2 * tid + 1;
      float e0 = (epart[t0] + epart[512 + t0] + epart[1024 + t0] + epart[1536 + t0]) * 2.0f;
      float e1 = (epart[t1] + epart[512 + t1] + epart[1024 + t1] + epart[1536 + t1]) * 2.0f;
      float m = fmaxf((t0 < hlen) ? e0 : -3e38f, (t1 < hlen) ? e1 : -3e38f);
#pragma unroll
      for (int off = 1; off < 64; off <<= 1) m = fmaxf(m, __shfl_xor(m, off));
      if (lane == 0) red[wid] = m;
      __syncthreads();
      const float M = fmaxf(fmaxf(red[0], red[1]), fmaxf(red[2], red[3]));
      float w0 = (t0 < hlen) ? __expf(e0 - M) : 0.f;
      float w1 = (t1 < hlen) ? __expf(e1 - M) : 0.f;
      wL[t0] = w0; wL[t1] = w1;
      float sm = w0 + w1;
#pragma unroll
      for (int off = 1; off < 64; off <<= 1) sm += __shfl_xor(sm, off);
      __syncthreads();               // wL visible + red reusable
      if (lane == 0) red[wid] = sm;
      __syncthreads();
      const float inv = 1.0f / (red[0] + red[1] + red[2] + red[3]);
      // ---- att_c partials: wave w covers t chunk, bounded by hlen ----
      {
        float ac[8] = {0.f,0.f,0.f,0.f,0.f,0.f,0.f,0.f};
        const int tbase = wid * 128;
        const int tcnt = (hlen > tbase) ? ((hlen - tbase < 128) ? (hlen - tbase) : 128) : 0;
#pragma unroll 8
        for (int tt = 0; tt < tcnt; ++tt) {
          const int t = tbase + tt;
          f16x8 hv = *(const f16x8*)(ph + (long)t * 512 + lane * 8);
          const float w = wL[t];
#pragma unroll
          for (int j = 0; j < 8; ++j) ac[j] += (float)hv[j] * w;
        }
#pragma unroll
        for (int j = 0; j < 8; ++j) apart[wid * 512 + lane * 8 + j] = ac[j];
      }
      __syncthreads();
      {
        float s0 = apart[t0] + apart[512 + t0] + apart[1024 + t0] + apart[1536 + t0];
        float s1 = apart[t1] + apart[512 + t1] + apart[1024 + t1] + apart[1536 + t1];
        astore32((unsigned*)(p.att + (long)s * (NB * NE)) + b * 256 + tid,
                 pack2(s0 * inv, s1 * inv));
      }
      __syncthreads();
      if (tid == 0)
        sigstep(p.bar, S_SATT + (b & 3), 8u * (s + 1), R_SATT, 4u * (s + 1),
                F_SATT, 16, (unsigned)(s + 1));
    }
  }
}

// ------------------------- logits GEMM + fused CE stats --------------------
__global__ void __launch_bounds__(256) k_lgemm(const f16* __restrict__ z, const f16* __restrict__ wout,
                                               const float* __restrict__ bout, float4* __restrict__ part) {
  const int mb = blockIdx.x, nb = blockIdx.y;
  const int wid = threadIdx.x >> 6, lane = threadIdx.x & 63;
  const int lr = lane & 15, lq = lane >> 4;
  const int m0 = mb * 32;
  const int n0 = nb * 512 + wid * 128;
  const f16* arow0 = z + (long)(m0 + lr) * 1024 + lq * 8;
  const f16* arow1 = arow0 + (long)16 * 1024;
  const f16* bp[8];
  int cols[8];
#pragma unroll
  for (int nt = 0; nt < 8; ++nt) {
    int n = n0 + nt * 16 + lr;
    cols[nt] = n;
    int nc = (n < NO) ? n : (NO - 1);
    bp[nt] = wout + (long)nc * 1024 + lq * 8;
  }
  f32x4 acc[16];
#pragma unroll
  for (int i = 0; i < 16; ++i) acc[i] = (f32x4){0.f, 0.f, 0.f, 0.f};
  for (int kk = 0; kk < 1024; kk += 32) {
    f16x8 a0v = *(const f16x8*)(arow0 + kk);
    f16x8 a1v = *(const f16x8*)(arow1 + kk);
#pragma unroll
    for (int nt = 0; nt < 8; ++nt) {
      f16x8 bv = *(const f16x8*)(bp[nt] + kk);
      acc[nt]     = __builtin_amdgcn_mfma_f32_16x16x32_f16(a0v, bv, acc[nt], 0, 0, 0);
      acc[8 + nt] = __builtin_amdgcn_mfma_f32_16x16x32_f16(a1v, bv, acc[8 + nt], 0, 0, 0);
    }
  }
  float bias[8];
#pragma unroll
  for (int nt = 0; nt < 8; ++nt) bias[nt] = (cols[nt] < NO) ? bout[cols[nt]] : 0.f;
  const int chunk = nb * 4 + wid;
#pragma unroll
  for (int mt = 0; mt < 2; ++mt) {
#pragma unroll
    for (int reg = 0; reg < 4; ++reg) {
      float vals[8];
      float mx = -1e30f, av = -1e30f; int ai = 0;
#pragma unroll
      for (int nt = 0; nt < 8; ++nt) {
        float v = (cols[nt] < NO) ? (acc[mt * 8 + nt][reg] + bias[nt]) : -1e30f;
        vals[nt] = v;
        mx = fmaxf(mx, v);
        if (v > av) { av = v; ai = cols[nt]; }
      }
      float sum = 0.f;
#pragma unroll
      for (int nt = 0; nt < 8; ++nt) sum += (vals[nt] > -9e29f) ? __expf(vals[nt] - mx) : 0.f;
#pragma unroll
      for (int off = 1; off < 16; off <<= 1) {
        float mo = __shfl_xor(mx, off);
        float so = __shfl_xor(sum, off);
        float avo = __shfl_xor(av, off);
        int aio = __shfl_xor(ai, off);
        float nm = fmaxf(mx, mo);
        float e1 = (mx > -9e29f) ? __expf(mx - nm) : 0.f;
        float e2 = (mo > -9e29f) ? __expf(mo - nm) : 0.f;
        sum = sum * e1 + so * e2;
        mx = nm;
        if (avo > av || (avo == av && aio < ai)) { av = avo; ai = aio; }
      }
      if (lr == 0) {
        int rowg = m0 + mt * 16 + lq * 4 + reg;
        float4 q; q.x = mx; q.y = sum; q.z = av; q.w = __int_as_float(ai);
        part[(long)rowg * 80 + chunk] = q;
      }
    }
  }
}

__global__ void k_tl(const f16* __restrict__ z, const f16* __restrict__ wout,
                     const float* __restrict__ bout, const int* __restrict__ ys, float* __restrict__ tl) {
  const int tok = blockIdx.x * 4 + (threadIdx.x >> 6);
  const int lane = threadIdx.x & 63;
  if (tok >= NTOK) return;
  const int s = tok >> 5, b = tok & 31;
  const int tgt = (s < 128) ? ys[b * 128 + s] : SOS_ID;
  const f16x8* zp = (const f16x8*)(z + (long)tok * 1024);
  const f16x8* wp = (const f16x8*)(wout + (long)tgt * 1024);
  float acc = 0.f;
  acc = dot8(zp[lane], wp[lane], acc);
  acc = dot8(zp[64 + lane], wp[64 + lane], acc);
#pragma unroll
  for (int off = 32; off > 0; off >>= 1) acc += __shfl_xor(acc, off);
  if (lane == 0) tl[tok] = acc + bout[tgt];
}

__global__ void k_ce(const float4* __restrict__ part, const float* __restrict__ tl,
                     const int* __restrict__ ys, float* scal) {
  const int m = blockIdx.x * 256 + threadIdx.x;
  float nll = 0.f, okf = 0.f;
  if (m < NTOK) {
    float M = -1e30f, S = 0.f, av = -1e30f; int ai = 0;
    for (int c = 0; c < 80; ++c) {
      float4 q = part[(long)m * 80 + c];
      float qm = q.x, qs = q.y, qa = q.z; int qi = __float_as_int(q.w);
      float nm = fmaxf(M, qm);
      float e1 = (M > -9e29f) ? __expf(M - nm) : 0.f;
      float e2 = (qm > -9e29f) ? __expf(qm - nm) : 0.f;
      S = S * e1 + qs * e2; M = nm;
      if (qa > av || (qa == av && qi < ai)) { av = qa; ai = qi; }
    }
    float lse = M + __logf(S);
    int s = m >> 5, b = m & 31;
    int tgt = (s < 128) ? ys[b * 128 + s] : SOS_ID;
    nll = lse - tl[m];
    okf = (ai == tgt) ? 1.f : 0.f;
  }
  __shared__ float r1[256], r2[256];
  r1[threadIdx.x] = nll; r2[threadIdx.x] = okf; __syncthreads();
  for (int st = 128; st > 0; st >>= 1) {
    if (threadIdx.x < st) { r1[threadIdx.x] += r1[threadIdx.x + st]; r2[threadIdx.x] += r2[threadIdx.x + st]; }
    __syncthreads();
  }
  if (threadIdx.x == 0) { atomicAdd(&scal[0], r1[0]); atomicAdd(&scal[1], r2[0]); }
}

__global__ void k_final(const float* scal, float* out) {
  if (threadIdx.x == 0) {
    float loss = scal[0] * (128.f / 4128.f);
    out[0] = loss;
    out[1] = scal[1] * (1.f / 4128.f);
    out[2] = expf(loss / 32.f);
  }
}

// --------------------------------- launch ----------------------------------
extern "C" void kernel_launch(void* const* d_in, const int* in_sizes, int n_in,
                              void* d_out, int out_size, void* d_ws, size_t ws_size,
                              hipStream_t stream) {
  const float* hs_pad = (const float*)d_in[0];
  const int* hlens    = (const int*)d_in[1];
  const int* ys_pad   = (const int*)d_in[2];
  const float* embed  = (const float*)d_in[3];
  const float* Wenc   = (const float*)d_in[4];
  const float* benc   = (const float*)d_in[5];
  const float* Wdec   = (const float*)d_in[6];
  const float* Wih0   = (const float*)d_in[7];
  const float* Whh0   = (const float*)d_in[8];
  const float* bih0   = (const float*)d_in[9];
  const float* bhh0   = (const float*)d_in[10];
  const float* Wih1   = (const float*)d_in[11];
  const float* Whh1   = (const float*)d_in[12];
  const float* bih1   = (const float*)d_in[13];
  const float* bhh1   = (const float*)d_in[14];
  const float* Wout   = (const float*)d_in[15];
  const float* bout   = (const float*)d_in[16];
  float* out = (float*)d_out;
  (void)in_sizes; (void)n_in; (void)out_size; (void)ws_size;

  char* ws = (char*)d_ws;
  size_t off = 0;
  auto alloc = [&](size_t bytes) -> char* {
    char* pp = ws + off;
    off = (off + bytes + 255) & ~(size_t)255;
    return pp;
  };
  f16* hs16    = (f16*)alloc((size_t)NB * NTT * NE * 2);
  f16* preT    = (f16*)alloc((size_t)NB * NA * NTT * 2);
  f16* eys16   = (f16*)alloc((size_t)NL * NB * ND * 2);
  f16* w0cat   = (f16*)alloc((size_t)4096 * 2560 * 2);
  f16* w1cat   = (f16*)alloc((size_t)4096 * 2048 * 2);
  f16* wdec16  = (f16*)alloc((size_t)NA * ND * 2);
  f16* wenc16  = (f16*)alloc((size_t)NA * NE * 2);
  f16* wout16  = (f16*)alloc((size_t)NO * ND * 2);
  f16* zout    = (f16*)alloc((size_t)NTOK * ND * 2);
  f16* z0seq   = (f16*)alloc((size_t)NL * NB * ND * 2);
  f16* attseq  = (f16*)alloc((size_t)NL * NB * NE * 2);
  float* bs0   = (float*)alloc(4096 * 4);
  float* bs1   = (float*)alloc(4096 * 4);
  float* tl    = (float*)alloc((size_t)NTOK * 4);
  float4* part = (float4*)alloc((size_t)NTOK * 80 * 16);
  float* scal  = (float*)alloc(256);
  unsigned* bar = (unsigned*)alloc(16384);

  k_cvt<<<dim3(2048), dim3(256), 0, stream>>>(hs_pad, hs16, (long)NB * NTT * NE);
  k_cvt<<<dim3(256), dim3(256), 0, stream>>>(Wdec, wdec16, (long)NA * ND);
  k_cvt<<<dim3(128), dim3(256), 0, stream>>>(Wenc, wenc16, (long)NA * NE);
  k_cvt<<<dim3(2048), dim3(256), 0, stream>>>(Wout, wout16, (long)NO * ND);
  k_w0cat<<<dim3(10, 4096), dim3(256), 0, stream>>>(Wih0, Whh0, w0cat);
  k_w1cat<<<dim3(8, 4096), dim3(256), 0, stream>>>(Wih1, Whh1, w1cat);
  k_eys<<<dim3(4, NL * NB), dim3(256), 0, stream>>>(ys_pad, embed, eys16);
  k_pre<<<dim3(512), dim3(256), 0, stream>>>(hs16, wenc16, benc, preT);
  k_bias<<<dim3(16), dim3(256), 0, stream>>>(bih0, bhh0, bih1, bhh1, bs0, bs1);
  k_zero<<<dim3(128), dim3(256), 0, stream>>>(scal, bar);

  LoopP lp;
  lp.preT = preT; lp.hs = hs16; lp.eys = eys16; lp.w0 = w0cat; lp.w1 = w1cat; lp.wdec = wdec16;
  lp.bs0 = bs0; lp.bs1 = bs1; lp.hlens = hlens;
  lp.att = attseq; lp.z0seq = z0seq; lp.zout = zout; lp.bar = bar;
  k_loop<<<dim3(GRID_LOOP), dim3(256), 0, stream>>>(lp);

  k_tl<<<dim3(NTOK / 4), dim3(256), 0, stream>>>(zout, wout16, bout, ys_pad, tl);
  k_lgemm<<<dim3(129, 20), dim3(256), 0, stream>>>(zout, wout16, bout, part);
  k_ce<<<dim3(17), dim3(256), 0, stream>>>(part, tl, ys_pad, scal);
  k_final<<<dim3(1), dim3(64), 0, stream>>>(scal, out);
}